// Round 4
// baseline (643.160 us; speedup 1.0000x reference)
//
#include <hip/hip_runtime.h>
#include <math.h>
#include <stdint.h>

#define V_N 100000
#define E_N 300000
#define D_N 128
#define EPSV 1e-5f
#define NCHUNK 391   // ceil(V_N/256)
#define MPAD 100096  // 1564 * 64
#define NBLK_G 1564  // MPAD/64 gemm blocks

typedef _Float16 f16;
typedef f16 f16x8 __attribute__((ext_vector_type(8)));
typedef f16 f16x4 __attribute__((ext_vector_type(4)));
typedef f16 f16x2 __attribute__((ext_vector_type(2)));
typedef float f32x4 __attribute__((ext_vector_type(4)));

// async global->LDS, 16B per lane; lds base must be wave-uniform
#define GLD(g, l) __builtin_amdgcn_global_load_lds( \
    (__attribute__((address_space(1))) void*)(g),   \
    (__attribute__((address_space(3))) void*)(l), 16, 0, 0)

// ----------------- CSR build -----------------
__global__ __launch_bounds__(256) void k_count(const int* __restrict__ edges, int* __restrict__ deg) {
  int i = blockIdx.x * blockDim.x + threadIdx.x;
  if (i < 2 * E_N) atomicAdd(&deg[edges[i]], 1);
}

__global__ __launch_bounds__(256) void k_chunksum(const int* __restrict__ deg, int* __restrict__ csum) {
  __shared__ int red[256];
  int c = blockIdx.x, t = threadIdx.x;
  int i = c * 256 + t;
  red[t] = (i < V_N) ? deg[i] : 0;
  __syncthreads();
  for (int s = 128; s > 0; s >>= 1) {
    if (t < s) red[t] += red[t + s];
    __syncthreads();
  }
  if (t == 0) csum[c] = red[0];
}

__global__ __launch_bounds__(512) void k_scanchunks(const int* __restrict__ csum, int* __restrict__ coff) {
  __shared__ int sh[512];
  int t = threadIdx.x;
  int v = (t < NCHUNK) ? csum[t] : 0;
  sh[t] = v;
  __syncthreads();
  for (int s = 1; s < 512; s <<= 1) {
    int x = (t >= s) ? sh[t - s] : 0;
    __syncthreads();
    sh[t] += x;
    __syncthreads();
  }
  if (t < NCHUNK) coff[t] = sh[t] - v;  // exclusive
}

__global__ __launch_bounds__(256) void k_writeoff(const int* __restrict__ deg, const int* __restrict__ coff,
                                                  int* __restrict__ csr_off, float* __restrict__ dinv,
                                                  float* __restrict__ degf) {
  __shared__ int sh[256];
  int c = blockIdx.x, t = threadIdx.x;
  int i = c * 256 + t;
  int v = (i < V_N) ? deg[i] : 0;
  sh[t] = v;
  __syncthreads();
  for (int s = 1; s < 256; s <<= 1) {
    int x = (t >= s) ? sh[t - s] : 0;
    __syncthreads();
    sh[t] += x;
    __syncthreads();
  }
  int excl = sh[t] - v;
  if (i <= V_N) csr_off[i] = coff[c] + excl;
  if (i < V_N) {
    dinv[i] = 1.0f / (1.0f + (float)v);
    degf[i] = (float)v;
  }
}

// fills CSR adj AND the ELL8 fast-path array (first 8 neighbors at adjell[v*8+j]).
// Slots j >= deg stay uninitialized (workspace garbage) -> consumer clamps before use.
__global__ __launch_bounds__(256) void k_fill(const int* __restrict__ edges, const int* __restrict__ csr_off,
                                              int* __restrict__ cursor, int* __restrict__ adj,
                                              int* __restrict__ adjell) {
  int e = blockIdx.x * blockDim.x + threadIdx.x;
  if (e >= E_N) return;
  int s = edges[2 * e], d = edges[2 * e + 1];
  int p = atomicAdd(&cursor[s], 1);
  adj[csr_off[s] + p] = d;
  if (p < 8) adjell[s * 8 + p] = d;
  int q = atomicAdd(&cursor[d], 1);
  adj[csr_off[d] + q] = s;
  if (q < 8) adjell[d * 8 + q] = s;
}

// ----------------- merged prep: Wcat[l][n][k] half (k=[W0 row|W1 row]) + f16 cast of features --
__global__ __launch_bounds__(256) void k_prepcast(const float* __restrict__ W0, const float* __restrict__ W1,
                                                  f16* __restrict__ Wc, const float* __restrict__ x,
                                                  f16* __restrict__ y) {
  int b = blockIdx.x;
  if (b < 384) {  // 384*256 == 3*128*256 exactly
    int idx = b * 256 + threadIdx.x;
    int l = idx >> 15;
    int rem = idx & 32767;
    int n = rem >> 8, k = rem & 255;
    float v = (k < 128) ? W0[l * 16384 + n * 128 + k] : W1[l * 16384 + n * 128 + (k - 128)];
    Wc[idx] = (f16)v;
  } else {
    int q = (b - 384) * 256 + threadIdx.x;  // float4 index over V_N*128
    if (q >= V_N * 32) return;
    float4 xv = ((const float4*)x)[q];
    f16x4 h;
    h[0] = (f16)xv.x; h[1] = (f16)xv.y; h[2] = (f16)xv.z; h[3] = (f16)xv.w;
    *(f16x4*)&y[(size_t)q * 4] = h;
  }
}

// ----------------- gather: quad-per-vertex, dwordx4 row loads, packed-f16 math ----------
// Wave = 4 quads; quad q owns one vertex, lane l16 owns one 16B channel chunk (8 halves).
// Each neighbor-row load is one dwordx4 per lane -> one wave-instruction covers 4 rows.
// MODE 0: neighbors from y (raw). MODE 1: neighbors from tin with relu(scale*t+shift).
// ELL8 fast path (first 8 neighbors); tail (deg > 8) walks CSR, divergent per quad.
// Blocks 0..63 zero the 64 stats shards. Grid: 6250 blocks x 4 waves x 4 quads = 100000.
template <int MODE>
__global__ __launch_bounds__(256) void k_gather(const f16* __restrict__ tin, const f16* __restrict__ y,
                                                f16* __restrict__ xa, const int* __restrict__ deg,
                                                const int* __restrict__ csr_off,
                                                const int* __restrict__ adjell, const int* __restrict__ adj,
                                                const float* __restrict__ scale,
                                                const float* __restrict__ shift, float* __restrict__ stats) {
  if (blockIdx.x < 64) stats[blockIdx.x * 256 + threadIdx.x] = 0.f;
  int w = threadIdx.x >> 6, lane = threadIdx.x & 63;
  int q = lane >> 4, l16 = lane & 15;
  int v = (blockIdx.x * 4 + w) * 4 + q;  // this lane's vertex (exactly covers [0, V_N))
  int co = l16 * 8;                      // channel base, 8 halves = 16B
  const f16* base = MODE ? tin : y;
  f16x8 scv = {}, sfv = {};
  if (MODE) {
#pragma unroll
    for (int k = 0; k < 8; ++k) {
      scv[k] = (f16)scale[co + k];
      sfv[k] = (f16)shift[co + k];
    }
  }
  int dg = deg[v];
  int s0 = csr_off[v];
  int4 ia = *(const int4*)&adjell[v * 8];
  int4 ib = *(const int4*)&adjell[v * 8 + 4];
  int idx[8] = {ia.x, ia.y, ia.z, ia.w, ib.x, ib.y, ib.z, ib.w};
#pragma unroll
  for (int j = 0; j < 8; ++j) idx[j] = ((unsigned)idx[j] < (unsigned)V_N) ? idx[j] : 0;
  f16x8 h[8];
#pragma unroll
  for (int j = 0; j < 8; ++j) h[j] = *(const f16x8*)&base[(size_t)idx[j] * 128 + co];
  f16x8 zero = {};
#pragma unroll
  for (int j = 0; j < 8; ++j) {
    f16x8 u = h[j];
    if (MODE) u = __builtin_elementwise_max(scv * u + sfv, zero);
    h[j] = (j < dg) ? u : zero;
  }
  f16x8 t01 = h[0] + h[1], t23 = h[2] + h[3], t45 = h[4] + h[5], t67 = h[6] + h[7];
  f16x8 sum = (t01 + t23) + (t45 + t67);
  float a[8];
#pragma unroll
  for (int k = 0; k < 8; ++k) a[k] = (float)sum[k];
  // tail for deg > 8 (divergent at quad granularity; P ~ 11% of vertices)
  for (int p = 8; p < dg; p += 8) {
    int id2[8];
#pragma unroll
    for (int j = 0; j < 8; ++j) {
      int pp = p + j;
      id2[j] = adj[s0 + (pp < dg ? pp : dg - 1)];
    }
    f16x8 g[8];
#pragma unroll
    for (int j = 0; j < 8; ++j) g[j] = *(const f16x8*)&base[(size_t)id2[j] * 128 + co];
#pragma unroll
    for (int j = 0; j < 8; ++j) {
      f16x8 u = g[j];
      if (MODE) u = __builtin_elementwise_max(scv * u + sfv, zero);
      g[j] = (p + j < dg) ? u : zero;
    }
    f16x8 s2 = ((g[0] + g[1]) + (g[2] + g[3])) + ((g[4] + g[5]) + (g[6] + g[7]));
#pragma unroll
    for (int k = 0; k < 8; ++k) a[k] += (float)s2[k];
  }
  f16x8 o;
#pragma unroll
  for (int k = 0; k < 8; ++k) o[k] = (f16)a[k];
  *(f16x8*)&xa[(size_t)v * 128 + co] = o;
}

// ----------------- fused GEMM: t = dinv * ([act|xa] @ Wcat^T + b0 + deg*b1); + BN stats ---
// 64 rows x 128 cols per block (1564 blocks), K=256 in 4 chunks of 64 halves.
// MODE 0: A y-half = ysrc (raw f16) via global_load_lds.
// MODE 1: A y-half reg-staged from ysrc(=t, in-place safe: block reads only its own 64
//         rows before writing them) with relu(scale*t+shift) applied in f16 registers.
// Last-arriving block computes BN finalize (scale/shift for next layer) in its tail.
template <int MODE>
__global__ __launch_bounds__(256) void k_gemm(const f16* ysrc, const f16* __restrict__ xa,
                                              const f16* __restrict__ Wc,
                                              const float* __restrict__ b0, const float* __restrict__ b1,
                                              const float* __restrict__ dinv, const float* __restrict__ degf,
                                              const float* __restrict__ scale, const float* __restrict__ shift,
                                              const float* __restrict__ gamma, const float* __restrict__ beta,
                                              float* __restrict__ sc_out, float* __restrict__ sf_out,
                                              f16* tbuf, float* stats, int* __restrict__ cnt) {
  __shared__ __align__(16) f16 As[64 * 64];    // 512 x 16B chunks, chunk (r,c) at slot r*8 + (c^(r&7))
  __shared__ __align__(16) f16 Bs[128 * 64];   // 1024 x 16B chunks
  __shared__ float sstat[256];
  __shared__ __align__(16) f16 scf[128], shf[128];
  __shared__ bool lastb;
  int tid = threadIdx.x;
  int w = tid >> 6, lane = tid & 63;
  int quad = lane >> 4, l16 = lane & 15;
  int row0 = blockIdx.x * 64;
  f32x4 acc[8] = {};
  sstat[tid] = 0.f;
  if (MODE) {
    if (tid < 128) {
      scf[tid] = (f16)scale[tid];
      shf[tid] = (f16)shift[tid];
    }
    __syncthreads();  // scf/shf visible before reg-staging reads them
  }

  for (int kc = 0; kc < 4; ++kc) {
    if (MODE && kc < 2) {
      // reg-stage A from t with on-the-fly BN+relu (identical f16 math to old gather y-path)
      int koff = kc * 64;
      f16x8 zero = {};
#pragma unroll
      for (int i = 0; i < 2; ++i) {
        int s = (w * 2 + i) * 64 + lane;
        int r = s >> 3, c = (s & 7) ^ (r & 7);
        int ch = koff + c * 8;
        f16x8 u = *(const f16x8*)&ysrc[(size_t)(row0 + r) * 128 + ch];
        f16x8 sc8 = *(const f16x8*)&scf[ch];
        f16x8 sf8 = *(const f16x8*)&shf[ch];
        u = __builtin_elementwise_max(sc8 * u + sf8, zero);
        *(f16x8*)&As[s * 8] = u;
      }
    } else {
      const f16* Abase = (kc < 2) ? ysrc : xa;
      int koff = (kc & 1) * 64;
#pragma unroll
      for (int i = 0; i < 2; ++i) {
        int s = (w * 2 + i) * 64 + lane;
        int r = s >> 3, c = (s & 7) ^ (r & 7);
        GLD(Abase + (size_t)(row0 + r) * 128 + koff + c * 8, &As[(w * 2 + i) * 512]);
      }
    }
    // stage B: 1024 chunks, 4 per wave
#pragma unroll
    for (int i = 0; i < 4; ++i) {
      int s = (w * 4 + i) * 64 + lane;
      int r = s >> 3, c = (s & 7) ^ (r & 7);
      GLD(Wc + (size_t)r * 256 + kc * 64 + c * 8, &Bs[(w * 4 + i) * 512]);
    }
    __syncthreads();  // drains vmcnt (GLD) + lgkmcnt (ds_write) + barrier
#pragma unroll
    for (int ks = 0; ks < 2; ++ks) {
      int cc = ks * 4 + quad;
      int rr = w * 16 + l16;
      f16x8 af = *(const f16x8*)&As[(rr * 8 + (cc ^ (rr & 7))) * 8];
#pragma unroll
      for (int ni = 0; ni < 8; ++ni) {
        int rb = ni * 16 + l16;
        f16x8 bf = *(const f16x8*)&Bs[(rb * 8 + (cc ^ (rb & 7))) * 8];
        acc[ni] = __builtin_amdgcn_mfma_f32_16x16x32_f16(af, bf, acc[ni], 0, 0, 0);
      }
    }
    __syncthreads();
  }

  float b0c[8], b1c[8];
#pragma unroll
  for (int ni = 0; ni < 8; ++ni) {
    b0c[ni] = b0[ni * 16 + l16];
    b1c[ni] = b1[ni * 16 + l16];
  }
  float csum[8] = {}, csq[8] = {};
  // C/D layout: col = l16, row = quad*4 + reg
#pragma unroll
  for (int reg = 0; reg < 4; ++reg) {
    int v = row0 + w * 16 + quad * 4 + reg;
    if (v < V_N) {
      float dv = dinv[v], gf = degf[v];
#pragma unroll
      for (int ni = 0; ni < 8; ++ni) {
        float tv = dv * (acc[ni][reg] + b0c[ni] + gf * b1c[ni]);
        tbuf[(size_t)v * 128 + ni * 16 + l16] = (f16)tv;
        csum[ni] += tv;
        csq[ni] += tv * tv;
      }
    }
  }
#pragma unroll
  for (int ni = 0; ni < 8; ++ni) {
    csum[ni] += __shfl_xor(csum[ni], 16);
    csum[ni] += __shfl_xor(csum[ni], 32);
    csq[ni] += __shfl_xor(csq[ni], 16);
    csq[ni] += __shfl_xor(csq[ni], 32);
  }
  if (quad == 0) {
#pragma unroll
    for (int ni = 0; ni < 8; ++ni) {
      atomicAdd(&sstat[ni * 16 + l16], csum[ni]);
      atomicAdd(&sstat[128 + ni * 16 + l16], csq[ni]);
    }
  }
  __syncthreads();
  atomicAdd(&stats[(blockIdx.x & 63) * 256 + tid], sstat[tid]);  // 64-way sharded

  // ---- tail-block BN finalize (replaces separate k_finalize launch) ----
  __threadfence();  // release our stats adds
  if (tid == 0) {
    int old = atomicAdd(cnt, 1);
    lastb = (old == NBLK_G - 1);
  }
  __syncthreads();
  if (lastb) {
    __threadfence();  // acquire all blocks' stats adds
    if (tid < 128) {
      float s = 0.f, sq = 0.f;
#pragma unroll 8
      for (int h = 0; h < 64; ++h) {
        s += __hip_atomic_load(&stats[h * 256 + tid], __ATOMIC_RELAXED, __HIP_MEMORY_SCOPE_AGENT);
        sq += __hip_atomic_load(&stats[h * 256 + 128 + tid], __ATOMIC_RELAXED, __HIP_MEMORY_SCOPE_AGENT);
      }
      float mu = s * (1.0f / V_N);
      float var = sq * (1.0f / V_N) - mu * mu;
      float scv = gamma[tid] * rsqrtf(var + EPSV);
      sc_out[tid] = scv;
      sf_out[tid] = beta[tid] - mu * scv;
    }
  }
}

// ----------------- final: out = relu(scale*t + shift + features) -----------------
__global__ __launch_bounds__(256) void k_final(const f16* __restrict__ t, const float* __restrict__ feat,
                                               const float* __restrict__ scale, const float* __restrict__ shift,
                                               float* __restrict__ out) {
  int q = blockIdx.x * 256 + threadIdx.x;  // float4 index
  if (q >= V_N * 32) return;
  int c4 = q & 31;
  f16x4 tv = *(const f16x4*)&t[(size_t)q * 4];
  float4 fv = ((const float4*)feat)[q];
  float4 sc = ((const float4*)scale)[c4];
  float4 sf = ((const float4*)shift)[c4];
  float4 o;
  o.x = fmaxf(sc.x * (float)tv[0] + sf.x + fv.x, 0.f);
  o.y = fmaxf(sc.y * (float)tv[1] + sf.y + fv.y, 0.f);
  o.z = fmaxf(sc.z * (float)tv[2] + sf.z + fv.z, 0.f);
  o.w = fmaxf(sc.w * (float)tv[3] + sf.w + fv.w, 0.f);
  ((float4*)out)[q] = o;
}

extern "C" void kernel_launch(void* const* d_in, const int* in_sizes, int n_in,
                              void* d_out, int out_size, void* d_ws, size_t ws_size,
                              hipStream_t stream) {
  const float* features = (const float*)d_in[0];
  const int* edges = (const int*)d_in[1];
  const float* W0 = (const float*)d_in[2];
  const float* b0 = (const float*)d_in[3];
  const float* W1 = (const float*)d_in[4];
  const float* b1 = (const float*)d_in[5];
  const float* gamma = (const float*)d_in[6];
  const float* beta = (const float*)d_in[7];
  float* out = (float*)d_out;

  char* ws = (char*)d_ws;
  size_t off = 0;
  auto alloc = [&](size_t bytes) -> void* {
    void* p = ws + off;
    off = (off + bytes + 255) & ~(size_t)255;
    return p;
  };
  int* deg = (int*)alloc((size_t)V_N * 4);
  int* csr_off = (int*)alloc((size_t)(V_N + 1) * 4);
  int* adj = (int*)alloc((size_t)2 * E_N * 4);
  int* adjell = (int*)alloc((size_t)V_N * 8 * 4);
  float* dinv = (float*)alloc((size_t)V_N * 4);
  float* degf = (float*)alloc((size_t)V_N * 4);
  int* csum = (int*)alloc(512 * 4);
  int* coff = (int*)alloc(512 * 4);
  float* stats = (float*)alloc(64 * 256 * 4 + 256);  // + per-layer counters
  int* cnt = (int*)(stats + 64 * 256);
  float* scale = (float*)alloc(128 * 4);
  float* shift = (float*)alloc(128 * 4);
  f16* y = (f16*)alloc((size_t)MPAD * 128 * 2);
  f16* xa = (f16*)alloc((size_t)MPAD * 128 * 2);
  f16* tbuf = (f16*)alloc((size_t)MPAD * 128 * 2);
  f16* Wcat = (f16*)alloc((size_t)3 * 128 * 256 * 2);

  // CSR + ELL8 + dinv/degf
  hipMemsetAsync(deg, 0, (size_t)V_N * 4, stream);
  k_count<<<(2 * E_N + 255) / 256, 256, 0, stream>>>(edges, deg);
  k_chunksum<<<NCHUNK, 256, 0, stream>>>(deg, csum);
  k_scanchunks<<<1, 512, 0, stream>>>(csum, coff);
  k_writeoff<<<NCHUNK, 256, 0, stream>>>(deg, coff, csr_off, dinv, degf);
  hipMemsetAsync(deg, 0, (size_t)V_N * 4, stream);
  k_fill<<<(E_N + 255) / 256, 256, 0, stream>>>(edges, csr_off, deg, adj, adjell);
  // after k_fill, deg (cursor) == degree again
  k_prepcast<<<384 + 12500, 256, 0, stream>>>(W0, W1, Wcat, features, y);
  hipMemsetAsync(stats, 0, (size_t)64 * 256 * 4 + 256, stream);

  // layer 0: gather from y (raw), gemm A y-half = y via GLD
  k_gather<0><<<6250, 256, 0, stream>>>(tbuf, y, xa, deg, csr_off, adjell, adj, scale, shift, stats);
  k_gemm<0><<<NBLK_G, 256, 0, stream>>>(y, xa, Wcat, b0, b1, dinv, degf, scale, shift,
                                        gamma, beta, scale, shift, tbuf, stats, &cnt[0]);
  // layers 1,2: gather from t with BN+relu; gemm reg-stages act(t) as A y-half (in-place on tbuf)
  for (int l = 1; l < 3; ++l) {
    k_gather<1><<<6250, 256, 0, stream>>>(tbuf, y, xa, deg, csr_off, adjell, adj, scale, shift, stats);
    k_gemm<1><<<NBLK_G, 256, 0, stream>>>(tbuf, xa, Wcat + (size_t)l * 128 * 256, b0 + l * D_N,
                                          b1 + l * D_N, dinv, degf, scale, shift,
                                          gamma + l * D_N, beta + l * D_N, scale, shift,
                                          tbuf, stats, &cnt[l]);
  }
  k_final<<<12500, 256, 0, stream>>>(tbuf, features, scale, shift, out);
}

// Round 5
// 355.161 us; speedup vs baseline: 1.8109x; 1.8109x over previous
//
#include <hip/hip_runtime.h>
#include <math.h>
#include <stdint.h>

#define V_N 100000
#define E_N 300000
#define D_N 128
#define EPSV 1e-5f
#define NCHUNK 391   // ceil(V_N/256)
#define MPAD 100096  // 1564 * 64
#define NBLK_G 1564  // MPAD/64 gemm blocks

typedef _Float16 f16;
typedef f16 f16x8 __attribute__((ext_vector_type(8)));
typedef f16 f16x4 __attribute__((ext_vector_type(4)));
typedef f16 f16x2 __attribute__((ext_vector_type(2)));
typedef float f32x4 __attribute__((ext_vector_type(4)));

// async global->LDS, 16B per lane; lds base must be wave-uniform
#define GLD(g, l) __builtin_amdgcn_global_load_lds( \
    (__attribute__((address_space(1))) void*)(g),   \
    (__attribute__((address_space(3))) void*)(l), 16, 0, 0)

// ----------------- CSR build -----------------
__global__ __launch_bounds__(256) void k_count(const int* __restrict__ edges, int* __restrict__ deg) {
  int i = blockIdx.x * blockDim.x + threadIdx.x;
  if (i < 2 * E_N) atomicAdd(&deg[edges[i]], 1);
}

__global__ __launch_bounds__(256) void k_chunksum(const int* __restrict__ deg, int* __restrict__ csum) {
  __shared__ int red[256];
  int c = blockIdx.x, t = threadIdx.x;
  int i = c * 256 + t;
  red[t] = (i < V_N) ? deg[i] : 0;
  __syncthreads();
  for (int s = 128; s > 0; s >>= 1) {
    if (t < s) red[t] += red[t + s];
    __syncthreads();
  }
  if (t == 0) csum[c] = red[0];
}

__global__ __launch_bounds__(512) void k_scanchunks(const int* __restrict__ csum, int* __restrict__ coff) {
  __shared__ int sh[512];
  int t = threadIdx.x;
  int v = (t < NCHUNK) ? csum[t] : 0;
  sh[t] = v;
  __syncthreads();
  for (int s = 1; s < 512; s <<= 1) {
    int x = (t >= s) ? sh[t - s] : 0;
    __syncthreads();
    sh[t] += x;
    __syncthreads();
  }
  if (t < NCHUNK) coff[t] = sh[t] - v;  // exclusive
}

__global__ __launch_bounds__(256) void k_writeoff(const int* __restrict__ deg, const int* __restrict__ coff,
                                                  int* __restrict__ csr_off, float* __restrict__ dinv,
                                                  float* __restrict__ degf) {
  __shared__ int sh[256];
  int c = blockIdx.x, t = threadIdx.x;
  int i = c * 256 + t;
  int v = (i < V_N) ? deg[i] : 0;
  sh[t] = v;
  __syncthreads();
  for (int s = 1; s < 256; s <<= 1) {
    int x = (t >= s) ? sh[t - s] : 0;
    __syncthreads();
    sh[t] += x;
    __syncthreads();
  }
  int excl = sh[t] - v;
  if (i <= V_N) csr_off[i] = coff[c] + excl;
  if (i < V_N) {
    dinv[i] = 1.0f / (1.0f + (float)v);
    degf[i] = (float)v;
  }
}

// fills CSR adj AND the ELL8 fast-path array (first 8 neighbors at adjell[v*8+j]).
// Slots j >= deg stay uninitialized (workspace garbage) -> consumer clamps before use.
__global__ __launch_bounds__(256) void k_fill(const int* __restrict__ edges, const int* __restrict__ csr_off,
                                              int* __restrict__ cursor, int* __restrict__ adj,
                                              int* __restrict__ adjell) {
  int e = blockIdx.x * blockDim.x + threadIdx.x;
  if (e >= E_N) return;
  int s = edges[2 * e], d = edges[2 * e + 1];
  int p = atomicAdd(&cursor[s], 1);
  adj[csr_off[s] + p] = d;
  if (p < 8) adjell[s * 8 + p] = d;
  int q = atomicAdd(&cursor[d], 1);
  adj[csr_off[d] + q] = s;
  if (q < 8) adjell[d * 8 + q] = s;
}

// ----------------- merged prep: Wcat[l][n][k] half (k=[W0 row|W1 row]) + f16 cast of features --
__global__ __launch_bounds__(256) void k_prepcast(const float* __restrict__ W0, const float* __restrict__ W1,
                                                  f16* __restrict__ Wc, const float* __restrict__ x,
                                                  f16* __restrict__ y) {
  int b = blockIdx.x;
  if (b < 384) {  // 384*256 == 3*128*256 exactly
    int idx = b * 256 + threadIdx.x;
    int l = idx >> 15;
    int rem = idx & 32767;
    int n = rem >> 8, k = rem & 255;
    float v = (k < 128) ? W0[l * 16384 + n * 128 + k] : W1[l * 16384 + n * 128 + (k - 128)];
    Wc[idx] = (f16)v;
  } else {
    int q = (b - 384) * 256 + threadIdx.x;  // float4 index over V_N*128
    if (q >= V_N * 32) return;
    float4 xv = ((const float4*)x)[q];
    f16x4 h;
    h[0] = (f16)xv.x; h[1] = (f16)xv.y; h[2] = (f16)xv.z; h[3] = (f16)xv.w;
    *(f16x4*)&y[(size_t)q * 4] = h;
  }
}

// ----------------- gather: quad-per-vertex, dwordx4 row loads, packed-f16 math ----------
// Wave = 4 quads; quad q owns one vertex, lane l16 owns one 16B channel chunk (8 halves).
// Each neighbor-row load is one dwordx4 per lane -> one wave-instruction covers 4 rows.
// MODE 0: neighbors from y (raw). MODE 1: neighbors from tin with relu(scale*t+shift).
// ELL8 fast path (first 8 neighbors); tail (deg > 8) walks CSR, divergent per quad.
// Blocks 0..63 zero the 64 stats shards. Grid: 6250 blocks x 4 waves x 4 quads = 100000.
template <int MODE>
__global__ __launch_bounds__(256) void k_gather(const f16* __restrict__ tin, const f16* __restrict__ y,
                                                f16* __restrict__ xa, const int* __restrict__ deg,
                                                const int* __restrict__ csr_off,
                                                const int* __restrict__ adjell, const int* __restrict__ adj,
                                                const float* __restrict__ scale,
                                                const float* __restrict__ shift, float* __restrict__ stats) {
  if (blockIdx.x < 64) stats[blockIdx.x * 256 + threadIdx.x] = 0.f;
  int w = threadIdx.x >> 6, lane = threadIdx.x & 63;
  int q = lane >> 4, l16 = lane & 15;
  int v = (blockIdx.x * 4 + w) * 4 + q;  // this lane's vertex (exactly covers [0, V_N))
  int co = l16 * 8;                      // channel base, 8 halves = 16B
  const f16* base = MODE ? tin : y;
  f16x8 scv = {}, sfv = {};
  if (MODE) {
#pragma unroll
    for (int k = 0; k < 8; ++k) {
      scv[k] = (f16)scale[co + k];
      sfv[k] = (f16)shift[co + k];
    }
  }
  int dg = deg[v];
  int s0 = csr_off[v];
  int4 ia = *(const int4*)&adjell[v * 8];
  int4 ib = *(const int4*)&adjell[v * 8 + 4];
  int idx[8] = {ia.x, ia.y, ia.z, ia.w, ib.x, ib.y, ib.z, ib.w};
#pragma unroll
  for (int j = 0; j < 8; ++j) idx[j] = ((unsigned)idx[j] < (unsigned)V_N) ? idx[j] : 0;
  f16x8 h[8];
#pragma unroll
  for (int j = 0; j < 8; ++j) h[j] = *(const f16x8*)&base[(size_t)idx[j] * 128 + co];
  f16x8 zero = {};
#pragma unroll
  for (int j = 0; j < 8; ++j) {
    f16x8 u = h[j];
    if (MODE) u = __builtin_elementwise_max(scv * u + sfv, zero);
    h[j] = (j < dg) ? u : zero;
  }
  f16x8 t01 = h[0] + h[1], t23 = h[2] + h[3], t45 = h[4] + h[5], t67 = h[6] + h[7];
  f16x8 sum = (t01 + t23) + (t45 + t67);
  float a[8];
#pragma unroll
  for (int k = 0; k < 8; ++k) a[k] = (float)sum[k];
  // tail for deg > 8 (divergent at quad granularity; P ~ 11% of vertices)
  for (int p = 8; p < dg; p += 8) {
    int id2[8];
#pragma unroll
    for (int j = 0; j < 8; ++j) {
      int pp = p + j;
      id2[j] = adj[s0 + (pp < dg ? pp : dg - 1)];
    }
    f16x8 g[8];
#pragma unroll
    for (int j = 0; j < 8; ++j) g[j] = *(const f16x8*)&base[(size_t)id2[j] * 128 + co];
#pragma unroll
    for (int j = 0; j < 8; ++j) {
      f16x8 u = g[j];
      if (MODE) u = __builtin_elementwise_max(scv * u + sfv, zero);
      g[j] = (p + j < dg) ? u : zero;
    }
    f16x8 s2 = ((g[0] + g[1]) + (g[2] + g[3])) + ((g[4] + g[5]) + (g[6] + g[7]));
#pragma unroll
    for (int k = 0; k < 8; ++k) a[k] += (float)s2[k];
  }
  f16x8 o;
#pragma unroll
  for (int k = 0; k < 8; ++k) o[k] = (f16)a[k];
  *(f16x8*)&xa[(size_t)v * 128 + co] = o;
}

// ----------------- fused GEMM: t = dinv * ([act|xa] @ Wcat^T + b0 + deg*b1); + BN stats ---
// 64 rows x 128 cols per block (1564 blocks), K=256 in 4 chunks of 64 halves.
// MODE 0: A y-half = ysrc (raw f16) via global_load_lds.
// MODE 1: A y-half reg-staged from ysrc(=t, in-place safe: block reads only its own 64
//         rows before writing them) with relu(scale*t+shift) applied in f16 registers.
template <int MODE>
__global__ __launch_bounds__(256) void k_gemm(const f16* ysrc, const f16* __restrict__ xa,
                                              const f16* __restrict__ Wc,
                                              const float* __restrict__ b0, const float* __restrict__ b1,
                                              const float* __restrict__ dinv, const float* __restrict__ degf,
                                              const float* __restrict__ scale, const float* __restrict__ shift,
                                              f16* tbuf, float* __restrict__ stats) {
  __shared__ __align__(16) f16 As[64 * 64];    // 512 x 16B chunks, chunk (r,c) at slot r*8 + (c^(r&7))
  __shared__ __align__(16) f16 Bs[128 * 64];   // 1024 x 16B chunks
  __shared__ float sstat[256];
  __shared__ __align__(16) f16 scf[128], shf[128];
  int tid = threadIdx.x;
  int w = tid >> 6, lane = tid & 63;
  int quad = lane >> 4, l16 = lane & 15;
  int row0 = blockIdx.x * 64;
  f32x4 acc[8] = {};
  sstat[tid] = 0.f;
  if (MODE) {
    if (tid < 128) {
      scf[tid] = (f16)scale[tid];
      shf[tid] = (f16)shift[tid];
    }
    __syncthreads();  // scf/shf visible before reg-staging reads them
  }

  for (int kc = 0; kc < 4; ++kc) {
    if (MODE && kc < 2) {
      // reg-stage A from t with on-the-fly BN+relu (identical f16 math to old gather y-path)
      int koff = kc * 64;
      f16x8 zero = {};
#pragma unroll
      for (int i = 0; i < 2; ++i) {
        int s = (w * 2 + i) * 64 + lane;
        int r = s >> 3, c = (s & 7) ^ (r & 7);
        int ch = koff + c * 8;
        f16x8 u = *(const f16x8*)&ysrc[(size_t)(row0 + r) * 128 + ch];
        f16x8 sc8 = *(const f16x8*)&scf[ch];
        f16x8 sf8 = *(const f16x8*)&shf[ch];
        u = __builtin_elementwise_max(sc8 * u + sf8, zero);
        *(f16x8*)&As[s * 8] = u;
      }
    } else {
      const f16* Abase = (kc < 2) ? ysrc : xa;
      int koff = (kc & 1) * 64;
#pragma unroll
      for (int i = 0; i < 2; ++i) {
        int s = (w * 2 + i) * 64 + lane;
        int r = s >> 3, c = (s & 7) ^ (r & 7);
        GLD(Abase + (size_t)(row0 + r) * 128 + koff + c * 8, &As[(w * 2 + i) * 512]);
      }
    }
    // stage B: 1024 chunks, 4 per wave
#pragma unroll
    for (int i = 0; i < 4; ++i) {
      int s = (w * 4 + i) * 64 + lane;
      int r = s >> 3, c = (s & 7) ^ (r & 7);
      GLD(Wc + (size_t)r * 256 + kc * 64 + c * 8, &Bs[(w * 4 + i) * 512]);
    }
    __syncthreads();  // drains vmcnt (GLD) + lgkmcnt (ds_write) + barrier
#pragma unroll
    for (int ks = 0; ks < 2; ++ks) {
      int cc = ks * 4 + quad;
      int rr = w * 16 + l16;
      f16x8 af = *(const f16x8*)&As[(rr * 8 + (cc ^ (rr & 7))) * 8];
#pragma unroll
      for (int ni = 0; ni < 8; ++ni) {
        int rb = ni * 16 + l16;
        f16x8 bf = *(const f16x8*)&Bs[(rb * 8 + (cc ^ (rb & 7))) * 8];
        acc[ni] = __builtin_amdgcn_mfma_f32_16x16x32_f16(af, bf, acc[ni], 0, 0, 0);
      }
    }
    __syncthreads();
  }

  float b0c[8], b1c[8];
#pragma unroll
  for (int ni = 0; ni < 8; ++ni) {
    b0c[ni] = b0[ni * 16 + l16];
    b1c[ni] = b1[ni * 16 + l16];
  }
  float csum[8] = {}, csq[8] = {};
  // C/D layout: col = l16, row = quad*4 + reg
#pragma unroll
  for (int reg = 0; reg < 4; ++reg) {
    int v = row0 + w * 16 + quad * 4 + reg;
    if (v < V_N) {
      float dv = dinv[v], gf = degf[v];
#pragma unroll
      for (int ni = 0; ni < 8; ++ni) {
        float tv = dv * (acc[ni][reg] + b0c[ni] + gf * b1c[ni]);
        tbuf[(size_t)v * 128 + ni * 16 + l16] = (f16)tv;
        csum[ni] += tv;
        csq[ni] += tv * tv;
      }
    }
  }
#pragma unroll
  for (int ni = 0; ni < 8; ++ni) {
    csum[ni] += __shfl_xor(csum[ni], 16);
    csum[ni] += __shfl_xor(csum[ni], 32);
    csq[ni] += __shfl_xor(csq[ni], 16);
    csq[ni] += __shfl_xor(csq[ni], 32);
  }
  if (quad == 0) {
#pragma unroll
    for (int ni = 0; ni < 8; ++ni) {
      atomicAdd(&sstat[ni * 16 + l16], csum[ni]);
      atomicAdd(&sstat[128 + ni * 16 + l16], csq[ni]);
    }
  }
  __syncthreads();
  atomicAdd(&stats[(blockIdx.x & 63) * 256 + tid], sstat[tid]);  // 64-way sharded
}

__global__ void k_finalize(const float* __restrict__ stats, const float* __restrict__ gamma,
                           const float* __restrict__ beta, float* __restrict__ scale,
                           float* __restrict__ shift) {
  int d = threadIdx.x;  // 128
  float s = 0.f, sq = 0.f;
#pragma unroll 8
  for (int h = 0; h < 64; ++h) {
    s += stats[h * 256 + d];
    sq += stats[h * 256 + 128 + d];
  }
  float mu = s * (1.0f / V_N);
  float var = sq * (1.0f / V_N) - mu * mu;
  float scv = gamma[d] * rsqrtf(var + EPSV);
  scale[d] = scv;
  shift[d] = beta[d] - mu * scv;
}

// ----------------- final: out = relu(scale*t + shift + features) -----------------
__global__ __launch_bounds__(256) void k_final(const f16* __restrict__ t, const float* __restrict__ feat,
                                               const float* __restrict__ scale, const float* __restrict__ shift,
                                               float* __restrict__ out) {
  int q = blockIdx.x * 256 + threadIdx.x;  // float4 index
  if (q >= V_N * 32) return;
  int c4 = q & 31;
  f16x4 tv = *(const f16x4*)&t[(size_t)q * 4];
  float4 fv = ((const float4*)feat)[q];
  float4 sc = ((const float4*)scale)[c4];
  float4 sf = ((const float4*)shift)[c4];
  float4 o;
  o.x = fmaxf(sc.x * (float)tv[0] + sf.x + fv.x, 0.f);
  o.y = fmaxf(sc.y * (float)tv[1] + sf.y + fv.y, 0.f);
  o.z = fmaxf(sc.z * (float)tv[2] + sf.z + fv.z, 0.f);
  o.w = fmaxf(sc.w * (float)tv[3] + sf.w + fv.w, 0.f);
  ((float4*)out)[q] = o;
}

extern "C" void kernel_launch(void* const* d_in, const int* in_sizes, int n_in,
                              void* d_out, int out_size, void* d_ws, size_t ws_size,
                              hipStream_t stream) {
  const float* features = (const float*)d_in[0];
  const int* edges = (const int*)d_in[1];
  const float* W0 = (const float*)d_in[2];
  const float* b0 = (const float*)d_in[3];
  const float* W1 = (const float*)d_in[4];
  const float* b1 = (const float*)d_in[5];
  const float* gamma = (const float*)d_in[6];
  const float* beta = (const float*)d_in[7];
  float* out = (float*)d_out;

  char* ws = (char*)d_ws;
  size_t off = 0;
  auto alloc = [&](size_t bytes) -> void* {
    void* p = ws + off;
    off = (off + bytes + 255) & ~(size_t)255;
    return p;
  };
  int* deg = (int*)alloc((size_t)V_N * 4);
  int* csr_off = (int*)alloc((size_t)(V_N + 1) * 4);
  int* adj = (int*)alloc((size_t)2 * E_N * 4);
  int* adjell = (int*)alloc((size_t)V_N * 8 * 4);
  float* dinv = (float*)alloc((size_t)V_N * 4);
  float* degf = (float*)alloc((size_t)V_N * 4);
  int* csum = (int*)alloc(512 * 4);
  int* coff = (int*)alloc(512 * 4);
  float* stats = (float*)alloc(64 * 256 * 4);
  float* scale = (float*)alloc(128 * 4);
  float* shift = (float*)alloc(128 * 4);
  f16* y = (f16*)alloc((size_t)MPAD * 128 * 2);
  f16* xa = (f16*)alloc((size_t)MPAD * 128 * 2);
  f16* tbuf = (f16*)alloc((size_t)MPAD * 128 * 2);
  f16* Wcat = (f16*)alloc((size_t)3 * 128 * 256 * 2);

  // CSR + ELL8 + dinv/degf
  hipMemsetAsync(deg, 0, (size_t)V_N * 4, stream);
  k_count<<<(2 * E_N + 255) / 256, 256, 0, stream>>>(edges, deg);
  k_chunksum<<<NCHUNK, 256, 0, stream>>>(deg, csum);
  k_scanchunks<<<1, 512, 0, stream>>>(csum, coff);
  k_writeoff<<<NCHUNK, 256, 0, stream>>>(deg, coff, csr_off, dinv, degf);
  hipMemsetAsync(deg, 0, (size_t)V_N * 4, stream);
  k_fill<<<(E_N + 255) / 256, 256, 0, stream>>>(edges, csr_off, deg, adj, adjell);
  // after k_fill, deg (cursor) == degree again
  k_prepcast<<<384 + 12500, 256, 0, stream>>>(W0, W1, Wcat, features, y);

  // layer 0: gather from y (raw), gemm A y-half = y via GLD
  k_gather<0><<<6250, 256, 0, stream>>>(tbuf, y, xa, deg, csr_off, adjell, adj, scale, shift, stats);
  k_gemm<0><<<NBLK_G, 256, 0, stream>>>(y, xa, Wcat, b0, b1, dinv, degf, scale, shift, tbuf, stats);
  k_finalize<<<1, 128, 0, stream>>>(stats, gamma, beta, scale, shift);
  // layers 1,2: gather from t with BN+relu; gemm reg-stages act(t) as A y-half (in-place on tbuf)
  for (int l = 1; l < 3; ++l) {
    k_gather<1><<<6250, 256, 0, stream>>>(tbuf, y, xa, deg, csr_off, adjell, adj, scale, shift, stats);
    k_gemm<1><<<NBLK_G, 256, 0, stream>>>(tbuf, xa, Wcat + (size_t)l * 128 * 256, b0 + l * D_N,
                                          b1 + l * D_N, dinv, degf, scale, shift, tbuf, stats);
    k_finalize<<<1, 128, 0, stream>>>(stats, gamma + l * D_N, beta + l * D_N, scale, shift);
  }
  k_final<<<12500, 256, 0, stream>>>(tbuf, features, scale, shift, out);
}

// Round 7
// 342.957 us; speedup vs baseline: 1.8753x; 1.0356x over previous
//
#include <hip/hip_runtime.h>
#include <math.h>
#include <stdint.h>

#define V_N 100000
#define E_N 300000
#define D_N 128
#define EPSV 1e-5f
#define NCHUNK 391   // ceil(V_N/256)
#define MPAD 100096  // 1564 * 64
#define NBLK_G 1564  // MPAD/64 gemm blocks
#define NSH 8        // stats shards

typedef _Float16 f16;
typedef f16 f16x8 __attribute__((ext_vector_type(8)));
typedef f16 f16x4 __attribute__((ext_vector_type(4)));
typedef f16 f16x2 __attribute__((ext_vector_type(2)));
typedef float f32x4 __attribute__((ext_vector_type(4)));

// async global->LDS, 16B per lane; lds base must be wave-uniform
#define GLD(g, l) __builtin_amdgcn_global_load_lds( \
    (__attribute__((address_space(1))) void*)(g),   \
    (__attribute__((address_space(3))) void*)(l), 16, 0, 0)

// ----------------- merged: edge-degree count + weight prep + feature cast -----------------
// blocks [0,2344): count; [2344,2728): Wcat[l][n][k] half, k=[W0 row|W1 row]; rest: f16 cast.
__global__ __launch_bounds__(256) void k_countprep(const int* __restrict__ edges, int* __restrict__ deg,
                                                   const float* __restrict__ W0, const float* __restrict__ W1,
                                                   f16* __restrict__ Wc, const float* __restrict__ x,
                                                   f16* __restrict__ y) {
  int b = blockIdx.x;
  if (b < 2344) {
    int i = b * 256 + threadIdx.x;
    if (i < 2 * E_N) atomicAdd(&deg[edges[i]], 1);
  } else if (b < 2344 + 384) {  // 384*256 == 3*128*256 exactly
    int idx = (b - 2344) * 256 + threadIdx.x;
    int l = idx >> 15;
    int rem = idx & 32767;
    int n = rem >> 8, k = rem & 255;
    float v = (k < 128) ? W0[l * 16384 + n * 128 + k] : W1[l * 16384 + n * 128 + (k - 128)];
    Wc[idx] = (f16)v;
  } else {
    int q = (b - 2344 - 384) * 256 + threadIdx.x;  // 12500*256 == V_N*32 exactly
    float4 xv = ((const float4*)x)[q];
    f16x4 h;
    h[0] = (f16)xv.x; h[1] = (f16)xv.y; h[2] = (f16)xv.z; h[3] = (f16)xv.w;
    *(f16x4*)&y[(size_t)q * 4] = h;
  }
}

__global__ __launch_bounds__(256) void k_chunksum(const int* __restrict__ deg, int* __restrict__ csum) {
  __shared__ int red[256];
  int c = blockIdx.x, t = threadIdx.x;
  int i = c * 256 + t;
  red[t] = (i < V_N) ? deg[i] : 0;
  __syncthreads();
  for (int s = 128; s > 0; s >>= 1) {
    if (t < s) red[t] += red[t + s];
    __syncthreads();
  }
  if (t == 0) csum[c] = red[0];
}

__global__ __launch_bounds__(512) void k_scanchunks(const int* __restrict__ csum, int* __restrict__ coff) {
  __shared__ int sh[512];
  int t = threadIdx.x;
  int v = (t < NCHUNK) ? csum[t] : 0;
  sh[t] = v;
  __syncthreads();
  for (int s = 1; s < 512; s <<= 1) {
    int x = (t >= s) ? sh[t - s] : 0;
    __syncthreads();
    sh[t] += x;
    __syncthreads();
  }
  if (t < NCHUNK) coff[t] = sh[t] - v;  // exclusive
}

// also zeroes the fill cursor (replaces a second memset of deg; deg stays = true degree)
__global__ __launch_bounds__(256) void k_writeoff(const int* __restrict__ deg, const int* __restrict__ coff,
                                                  int* __restrict__ csr_off, float* __restrict__ dinv,
                                                  float* __restrict__ degf, int* __restrict__ cursor) {
  __shared__ int sh[256];
  int c = blockIdx.x, t = threadIdx.x;
  int i = c * 256 + t;
  int v = (i < V_N) ? deg[i] : 0;
  sh[t] = v;
  __syncthreads();
  for (int s = 1; s < 256; s <<= 1) {
    int x = (t >= s) ? sh[t - s] : 0;
    __syncthreads();
    sh[t] += x;
    __syncthreads();
  }
  int excl = sh[t] - v;
  if (i <= V_N) csr_off[i] = coff[c] + excl;
  if (i < V_N) {
    dinv[i] = 1.0f / (1.0f + (float)v);
    degf[i] = (float)v;
    cursor[i] = 0;
  }
}

// fills CSR adj AND the ELL8 fast-path array (first 8 neighbors at adjell[v*8+j]).
// Slots j >= deg stay uninitialized (workspace garbage) -> consumer clamps before use.
__global__ __launch_bounds__(256) void k_fill(const int* __restrict__ edges, const int* __restrict__ csr_off,
                                              int* __restrict__ cursor, int* __restrict__ adj,
                                              int* __restrict__ adjell) {
  int e = blockIdx.x * blockDim.x + threadIdx.x;
  if (e >= E_N) return;
  int s = edges[2 * e], d = edges[2 * e + 1];
  int p = atomicAdd(&cursor[s], 1);
  adj[csr_off[s] + p] = d;
  if (p < 8) adjell[s * 8 + p] = d;
  int q = atomicAdd(&cursor[d], 1);
  adj[csr_off[d] + q] = s;
  if (q < 8) adjell[d * 8 + q] = s;
}

// ----------------- gather: quad-per-vertex, dwordx4 row loads, packed-f16 math ----------
// Wave = 4 quads; quad q owns one vertex, lane l16 owns one 16B channel chunk (8 halves).
// MODE 0: neighbors from y (raw). MODE 1: neighbors from tin with relu(scale*t+shift),
//   where scale/shift are recomputed PER BLOCK from statsP (8 shards, written by the
//   previous gemm kernel; stream order = visibility, no fences). Blocks 0..7 zero statsN.
// ELL8 fast path; tail (deg > 8) walks CSR. Grid: 6250 x 4 waves x 4 quads = 100000.
template <int MODE>
__global__ __launch_bounds__(256) void k_gather(const f16* __restrict__ tin, const f16* __restrict__ y,
                                                f16* __restrict__ xa, const int* __restrict__ deg,
                                                const int* __restrict__ csr_off,
                                                const int* __restrict__ adjell, const int* __restrict__ adj,
                                                const float* __restrict__ gamma, const float* __restrict__ beta,
                                                const float* __restrict__ statsP, float* __restrict__ statsN) {
  __shared__ float sred[256];
  __shared__ float scl[128], sfl[128];
  int tid = threadIdx.x;
  if (blockIdx.x < NSH) statsN[blockIdx.x * 256 + tid] = 0.f;
  int w = tid >> 6, lane = tid & 63;
  int q = lane >> 4, l16 = lane & 15;
  int v = (blockIdx.x * 4 + w) * 4 + q;  // this lane's vertex (exactly covers [0, V_N))
  int co = l16 * 8;                      // channel base, 8 halves = 16B
  const f16* base = MODE ? tin : y;
  int dg = deg[v];
  int s0 = csr_off[v];
  int4 ia = *(const int4*)&adjell[v * 8];
  int4 ib = *(const int4*)&adjell[v * 8 + 4];
  f16x8 scv = {}, sfv = {};
  if (MODE) {
    // per-block redundant BN finalize (identical f32 math in every block)
    float a = 0.f;
#pragma unroll
    for (int h = 0; h < NSH; ++h) a += statsP[h * 256 + tid];
    sred[tid] = a;
    __syncthreads();
    if (tid < 128) {
      float s = sred[tid], sq = sred[128 + tid];
      float mu = s * (1.0f / V_N);
      float var = sq * (1.0f / V_N) - mu * mu;
      float scvf = gamma[tid] * rsqrtf(var + EPSV);
      scl[tid] = scvf;
      sfl[tid] = beta[tid] - mu * scvf;
    }
    __syncthreads();
#pragma unroll
    for (int k = 0; k < 8; ++k) {
      scv[k] = (f16)scl[co + k];
      sfv[k] = (f16)sfl[co + k];
    }
  }
  int idx[8] = {ia.x, ia.y, ia.z, ia.w, ib.x, ib.y, ib.z, ib.w};
#pragma unroll
  for (int j = 0; j < 8; ++j) idx[j] = ((unsigned)idx[j] < (unsigned)V_N) ? idx[j] : 0;
  f16x8 h[8];
#pragma unroll
  for (int j = 0; j < 8; ++j) h[j] = *(const f16x8*)&base[(size_t)idx[j] * 128 + co];
  f16x8 zero = {};
#pragma unroll
  for (int j = 0; j < 8; ++j) {
    f16x8 u = h[j];
    if (MODE) u = __builtin_elementwise_max(scv * u + sfv, zero);
    h[j] = (j < dg) ? u : zero;
  }
  f16x8 t01 = h[0] + h[1], t23 = h[2] + h[3], t45 = h[4] + h[5], t67 = h[6] + h[7];
  f16x8 sum = (t01 + t23) + (t45 + t67);
  float a[8];
#pragma unroll
  for (int k = 0; k < 8; ++k) a[k] = (float)sum[k];
  // tail for deg > 8 (divergent at quad granularity; P ~ 11% of vertices)
  for (int p = 8; p < dg; p += 8) {
    int id2[8];
#pragma unroll
    for (int j = 0; j < 8; ++j) {
      int pp = p + j;
      id2[j] = adj[s0 + (pp < dg ? pp : dg - 1)];
    }
    f16x8 g[8];
#pragma unroll
    for (int j = 0; j < 8; ++j) g[j] = *(const f16x8*)&base[(size_t)id2[j] * 128 + co];
#pragma unroll
    for (int j = 0; j < 8; ++j) {
      f16x8 u = g[j];
      if (MODE) u = __builtin_elementwise_max(scv * u + sfv, zero);
      g[j] = (p + j < dg) ? u : zero;
    }
    f16x8 s2 = ((g[0] + g[1]) + (g[2] + g[3])) + ((g[4] + g[5]) + (g[6] + g[7]));
#pragma unroll
    for (int k = 0; k < 8; ++k) a[k] += (float)s2[k];
  }
  f16x8 o;
#pragma unroll
  for (int k = 0; k < 8; ++k) o[k] = (f16)a[k];
  *(f16x8*)&xa[(size_t)v * 128 + co] = o;
}

// ----------------- fused GEMM: t = dinv * ([act|xa] @ Wcat^T + b0 + deg*b1); + BN stats ---
// 64 rows x 128 cols per block (1564 blocks), K=256 in 4 chunks of 64 halves.
// MODE 0: A y-half = ysrc (raw f16) via global_load_lds.
// MODE 1: A y-half reg-staged from ysrc(=t, in-place safe) with relu(scale*t+shift);
//   scale/shift recomputed per block from statsP (previous layer's stats, prev kernel).
// Stats for THIS layer go to statsN (8-way sharded, zeroed by the preceding gather).
template <int MODE>
__global__ __launch_bounds__(256) void k_gemm(const f16* ysrc, const f16* __restrict__ xa,
                                              const f16* __restrict__ Wc,
                                              const float* __restrict__ b0, const float* __restrict__ b1,
                                              const float* __restrict__ dinv, const float* __restrict__ degf,
                                              const float* __restrict__ gammaP, const float* __restrict__ betaP,
                                              const float* __restrict__ statsP, float* __restrict__ statsN,
                                              f16* tbuf) {
  __shared__ __align__(16) f16 As[64 * 64];    // 512 x 16B chunks, chunk (r,c) at slot r*8 + (c^(r&7))
  __shared__ __align__(16) f16 Bs[128 * 64];   // 1024 x 16B chunks
  __shared__ float sstat[256];
  __shared__ __align__(16) f16 scf[128], shf[128];
  int tid = threadIdx.x;
  int w = tid >> 6, lane = tid & 63;
  int quad = lane >> 4, l16 = lane & 15;
  int row0 = blockIdx.x * 64;
  f32x4 acc[8] = {};
  if (MODE) {
    // per-block redundant BN finalize of the PREVIOUS layer (uses sstat as scratch)
    float a = 0.f;
#pragma unroll
    for (int h = 0; h < NSH; ++h) a += statsP[h * 256 + tid];
    sstat[tid] = a;
    __syncthreads();
    if (tid < 128) {
      float s = sstat[tid], sq = sstat[128 + tid];
      float mu = s * (1.0f / V_N);
      float var = sq * (1.0f / V_N) - mu * mu;
      float scv = gammaP[tid] * rsqrtf(var + EPSV);
      scf[tid] = (f16)scv;
      shf[tid] = (f16)(betaP[tid] - mu * scv);
    }
    __syncthreads();
  }
  sstat[tid] = 0.f;  // visible before epilogue use via the kc-loop barriers

  for (int kc = 0; kc < 4; ++kc) {
    if (MODE && kc < 2) {
      // reg-stage A from t with on-the-fly BN+relu (identical f16 math to gather's path)
      int koff = kc * 64;
      f16x8 zero = {};
#pragma unroll
      for (int i = 0; i < 2; ++i) {
        int s = (w * 2 + i) * 64 + lane;
        int r = s >> 3, c = (s & 7) ^ (r & 7);
        int ch = koff + c * 8;
        f16x8 u = *(const f16x8*)&ysrc[(size_t)(row0 + r) * 128 + ch];
        f16x8 sc8 = *(const f16x8*)&scf[ch];
        f16x8 sf8 = *(const f16x8*)&shf[ch];
        u = __builtin_elementwise_max(sc8 * u + sf8, zero);
        *(f16x8*)&As[s * 8] = u;
      }
    } else {
      const f16* Abase = (kc < 2) ? ysrc : xa;
      int koff = (kc & 1) * 64;
#pragma unroll
      for (int i = 0; i < 2; ++i) {
        int s = (w * 2 + i) * 64 + lane;
        int r = s >> 3, c = (s & 7) ^ (r & 7);
        GLD(Abase + (size_t)(row0 + r) * 128 + koff + c * 8, &As[(w * 2 + i) * 512]);
      }
    }
    // stage B: 1024 chunks, 4 per wave
#pragma unroll
    for (int i = 0; i < 4; ++i) {
      int s = (w * 4 + i) * 64 + lane;
      int r = s >> 3, c = (s & 7) ^ (r & 7);
      GLD(Wc + (size_t)r * 256 + kc * 64 + c * 8, &Bs[(w * 4 + i) * 512]);
    }
    __syncthreads();  // drains vmcnt (GLD) + lgkmcnt (ds_write) + barrier
#pragma unroll
    for (int ks = 0; ks < 2; ++ks) {
      int cc = ks * 4 + quad;
      int rr = w * 16 + l16;
      f16x8 af = *(const f16x8*)&As[(rr * 8 + (cc ^ (rr & 7))) * 8];
#pragma unroll
      for (int ni = 0; ni < 8; ++ni) {
        int rb = ni * 16 + l16;
        f16x8 bf = *(const f16x8*)&Bs[(rb * 8 + (cc ^ (rb & 7))) * 8];
        acc[ni] = __builtin_amdgcn_mfma_f32_16x16x32_f16(af, bf, acc[ni], 0, 0, 0);
      }
    }
    __syncthreads();
  }

  float b0c[8], b1c[8];
#pragma unroll
  for (int ni = 0; ni < 8; ++ni) {
    b0c[ni] = b0[ni * 16 + l16];
    b1c[ni] = b1[ni * 16 + l16];
  }
  float csum[8] = {}, csq[8] = {};
  // C/D layout: col = l16, row = quad*4 + reg
#pragma unroll
  for (int reg = 0; reg < 4; ++reg) {
    int v = row0 + w * 16 + quad * 4 + reg;
    if (v < V_N) {
      float dv = dinv[v], gf = degf[v];
#pragma unroll
      for (int ni = 0; ni < 8; ++ni) {
        float tv = dv * (acc[ni][reg] + b0c[ni] + gf * b1c[ni]);
        tbuf[(size_t)v * 128 + ni * 16 + l16] = (f16)tv;
        csum[ni] += tv;
        csq[ni] += tv * tv;
      }
    }
  }
#pragma unroll
  for (int ni = 0; ni < 8; ++ni) {
    csum[ni] += __shfl_xor(csum[ni], 16);
    csum[ni] += __shfl_xor(csum[ni], 32);
    csq[ni] += __shfl_xor(csq[ni], 16);
    csq[ni] += __shfl_xor(csq[ni], 32);
  }
  if (quad == 0) {
#pragma unroll
    for (int ni = 0; ni < 8; ++ni) {
      atomicAdd(&sstat[ni * 16 + l16], csum[ni]);
      atomicAdd(&sstat[128 + ni * 16 + l16], csq[ni]);
    }
  }
  __syncthreads();
  atomicAdd(&statsN[(blockIdx.x & (NSH - 1)) * 256 + tid], sstat[tid]);  // 8-way sharded
}

// ----------------- final: out = relu(scale*t + shift + features), scale/shift per block ---
__global__ __launch_bounds__(256) void k_final(const f16* __restrict__ t, const float* __restrict__ feat,
                                               const float* __restrict__ gamma, const float* __restrict__ beta,
                                               const float* __restrict__ stats, float* __restrict__ out) {
  __shared__ float sred[256];
  __shared__ float scl[128], sfl[128];
  int tid = threadIdx.x;
  float a = 0.f;
#pragma unroll
  for (int h = 0; h < NSH; ++h) a += stats[h * 256 + tid];
  sred[tid] = a;
  __syncthreads();
  if (tid < 128) {
    float s = sred[tid], sq = sred[128 + tid];
    float mu = s * (1.0f / V_N);
    float var = sq * (1.0f / V_N) - mu * mu;
    float scv = gamma[tid] * rsqrtf(var + EPSV);
    scl[tid] = scv;
    sfl[tid] = beta[tid] - mu * scv;
  }
  __syncthreads();
  int q = blockIdx.x * 256 + tid;  // float4 index; 12500*256 == V_N*32 exactly
  int c4 = (q & 31) * 4;
  f16x4 tv = *(const f16x4*)&t[(size_t)q * 4];
  float4 fv = ((const float4*)feat)[q];
  float4 o;
  o.x = fmaxf(scl[c4 + 0] * (float)tv[0] + sfl[c4 + 0] + fv.x, 0.f);
  o.y = fmaxf(scl[c4 + 1] * (float)tv[1] + sfl[c4 + 1] + fv.y, 0.f);
  o.z = fmaxf(scl[c4 + 2] * (float)tv[2] + sfl[c4 + 2] + fv.z, 0.f);
  o.w = fmaxf(scl[c4 + 3] * (float)tv[3] + sfl[c4 + 3] + fv.w, 0.f);
  ((float4*)out)[q] = o;
}

extern "C" void kernel_launch(void* const* d_in, const int* in_sizes, int n_in,
                              void* d_out, int out_size, void* d_ws, size_t ws_size,
                              hipStream_t stream) {
  const float* features = (const float*)d_in[0];
  const int* edges = (const int*)d_in[1];
  const float* W0 = (const float*)d_in[2];
  const float* b0 = (const float*)d_in[3];
  const float* W1 = (const float*)d_in[4];
  const float* b1 = (const float*)d_in[5];
  const float* gamma = (const float*)d_in[6];
  const float* beta = (const float*)d_in[7];
  float* out = (float*)d_out;

  char* ws = (char*)d_ws;
  size_t off = 0;
  auto alloc = [&](size_t bytes) -> void* {
    void* p = ws + off;
    off = (off + bytes + 255) & ~(size_t)255;
    return p;
  };
  int* deg = (int*)alloc((size_t)V_N * 4);
  int* cursor = (int*)alloc((size_t)V_N * 4);
  int* csr_off = (int*)alloc((size_t)(V_N + 1) * 4);
  int* adj = (int*)alloc((size_t)2 * E_N * 4);
  int* adjell = (int*)alloc((size_t)V_N * 8 * 4);
  float* dinv = (float*)alloc((size_t)V_N * 4);
  float* degf = (float*)alloc((size_t)V_N * 4);
  int* csum = (int*)alloc(512 * 4);
  int* coff = (int*)alloc(512 * 4);
  float* stats0 = (float*)alloc((size_t)NSH * 256 * 4);
  float* stats1 = (float*)alloc((size_t)NSH * 256 * 4);
  f16* y = (f16*)alloc((size_t)MPAD * 128 * 2);
  f16* xa = (f16*)alloc((size_t)MPAD * 128 * 2);
  f16* tbuf = (f16*)alloc((size_t)MPAD * 128 * 2);
  f16* Wcat = (f16*)alloc((size_t)3 * 128 * 256 * 2);

  // preamble: CSR + ELL8 + dinv/degf + weight prep + feature cast (6 dispatches)
  hipMemsetAsync(deg, 0, (size_t)V_N * 4, stream);
  k_countprep<<<2344 + 384 + 12500, 256, 0, stream>>>(edges, deg, W0, W1, Wcat, features, y);
  k_chunksum<<<NCHUNK, 256, 0, stream>>>(deg, csum);
  k_scanchunks<<<1, 512, 0, stream>>>(csum, coff);
  k_writeoff<<<NCHUNK, 256, 0, stream>>>(deg, coff, csr_off, dinv, degf, cursor);
  k_fill<<<(E_N + 255) / 256, 256, 0, stream>>>(edges, csr_off, cursor, adj, adjell);

  // layer 0: gather from y; gemm A y-half via GLD; stats -> stats0 (zeroed by gather<0>)
  k_gather<0><<<6250, 256, 0, stream>>>(tbuf, y, xa, deg, csr_off, adjell, adj,
                                        gamma, beta, stats0, stats0);
  k_gemm<0><<<NBLK_G, 256, 0, stream>>>(y, xa, Wcat, b0, b1, dinv, degf,
                                        gamma, beta, stats0, stats0, tbuf);
  // layer 1: BN(layer0) from stats0; stats -> stats1
  k_gather<1><<<6250, 256, 0, stream>>>(tbuf, y, xa, deg, csr_off, adjell, adj,
                                        gamma, beta, stats0, stats1);
  k_gemm<1><<<NBLK_G, 256, 0, stream>>>(tbuf, xa, Wcat + (size_t)1 * 128 * 256, b0 + D_N,
                                        b1 + D_N, dinv, degf, gamma, beta, stats0, stats1, tbuf);
  // layer 2: BN(layer1) from stats1; stats -> stats0
  k_gather<1><<<6250, 256, 0, stream>>>(tbuf, y, xa, deg, csr_off, adjell, adj,
                                        gamma + D_N, beta + D_N, stats1, stats0);
  k_gemm<1><<<NBLK_G, 256, 0, stream>>>(tbuf, xa, Wcat + (size_t)2 * 128 * 256, b0 + 2 * D_N,
                                        b1 + 2 * D_N, dinv, degf, gamma + D_N, beta + D_N,
                                        stats1, stats0, tbuf);
  // final: BN(layer2) from stats0 + residual + relu
  k_final<<<12500, 256, 0, stream>>>(tbuf, features, gamma + 2 * D_N, beta + 2 * D_N, stats0, out);
}

// Round 8
// 334.755 us; speedup vs baseline: 1.9213x; 1.0245x over previous
//
#include <hip/hip_runtime.h>
#include <math.h>
#include <stdint.h>

#define V_N 100000
#define E_N 300000
#define D_N 128
#define EPSV 1e-5f
#define NCHUNK 391   // ceil(V_N/256)
#define MPAD 100096  // 1564 * 64
#define NBLK_G 782   // MPAD/128 gemm blocks (128-row tiles)
#define NSH 8        // stats shards

typedef _Float16 f16;
typedef f16 f16x8 __attribute__((ext_vector_type(8)));
typedef f16 f16x4 __attribute__((ext_vector_type(4)));
typedef f16 f16x2 __attribute__((ext_vector_type(2)));
typedef float f32x4 __attribute__((ext_vector_type(4)));

// async global->LDS, 16B per lane; lds base must be wave-uniform
#define GLD(g, l) __builtin_amdgcn_global_load_lds( \
    (__attribute__((address_space(1))) void*)(g),   \
    (__attribute__((address_space(3))) void*)(l), 16, 0, 0)

// ----------------- merged: edge-degree count + weight prep + feature cast -----------------
// blocks [0,2344): count; [2344,2728): Wcat[l][n][k] half, k=[W0 row|W1 row]; rest: f16 cast.
__global__ __launch_bounds__(256) void k_countprep(const int* __restrict__ edges, int* __restrict__ deg,
                                                   const float* __restrict__ W0, const float* __restrict__ W1,
                                                   f16* __restrict__ Wc, const float* __restrict__ x,
                                                   f16* __restrict__ y) {
  int b = blockIdx.x;
  if (b < 2344) {
    int i = b * 256 + threadIdx.x;
    if (i < 2 * E_N) atomicAdd(&deg[edges[i]], 1);
  } else if (b < 2344 + 384) {  // 384*256 == 3*128*256 exactly
    int idx = (b - 2344) * 256 + threadIdx.x;
    int l = idx >> 15;
    int rem = idx & 32767;
    int n = rem >> 8, k = rem & 255;
    float v = (k < 128) ? W0[l * 16384 + n * 128 + k] : W1[l * 16384 + n * 128 + (k - 128)];
    Wc[idx] = (f16)v;
  } else {
    int q = (b - 2344 - 384) * 256 + threadIdx.x;  // 12500*256 == V_N*32 exactly
    float4 xv = ((const float4*)x)[q];
    f16x4 h;
    h[0] = (f16)xv.x; h[1] = (f16)xv.y; h[2] = (f16)xv.z; h[3] = (f16)xv.w;
    *(f16x4*)&y[(size_t)q * 4] = h;
  }
}

__global__ __launch_bounds__(256) void k_chunksum(const int* __restrict__ deg, int* __restrict__ csum) {
  __shared__ int red[256];
  int c = blockIdx.x, t = threadIdx.x;
  int i = c * 256 + t;
  red[t] = (i < V_N) ? deg[i] : 0;
  __syncthreads();
  for (int s = 128; s > 0; s >>= 1) {
    if (t < s) red[t] += red[t + s];
    __syncthreads();
  }
  if (t == 0) csum[c] = red[0];
}

__global__ __launch_bounds__(512) void k_scanchunks(const int* __restrict__ csum, int* __restrict__ coff) {
  __shared__ int sh[512];
  int t = threadIdx.x;
  int v = (t < NCHUNK) ? csum[t] : 0;
  sh[t] = v;
  __syncthreads();
  for (int s = 1; s < 512; s <<= 1) {
    int x = (t >= s) ? sh[t - s] : 0;
    __syncthreads();
    sh[t] += x;
    __syncthreads();
  }
  if (t < NCHUNK) coff[t] = sh[t] - v;  // exclusive
}

// also zeroes the fill cursor (replaces a second memset of deg; deg stays = true degree)
__global__ __launch_bounds__(256) void k_writeoff(const int* __restrict__ deg, const int* __restrict__ coff,
                                                  int* __restrict__ csr_off, float* __restrict__ dinv,
                                                  float* __restrict__ degf, int* __restrict__ cursor) {
  __shared__ int sh[256];
  int c = blockIdx.x, t = threadIdx.x;
  int i = c * 256 + t;
  int v = (i < V_N) ? deg[i] : 0;
  sh[t] = v;
  __syncthreads();
  for (int s = 1; s < 256; s <<= 1) {
    int x = (t >= s) ? sh[t - s] : 0;
    __syncthreads();
    sh[t] += x;
    __syncthreads();
  }
  int excl = sh[t] - v;
  if (i <= V_N) csr_off[i] = coff[c] + excl;
  if (i < V_N) {
    dinv[i] = 1.0f / (1.0f + (float)v);
    degf[i] = (float)v;
    cursor[i] = 0;
  }
}

// fills CSR adj AND the ELL8 fast-path array (first 8 neighbors at adjell[v*8+j]).
// Slots j >= deg stay uninitialized (workspace garbage) -> consumer clamps before use.
__global__ __launch_bounds__(256) void k_fill(const int* __restrict__ edges, const int* __restrict__ csr_off,
                                              int* __restrict__ cursor, int* __restrict__ adj,
                                              int* __restrict__ adjell) {
  int e = blockIdx.x * blockDim.x + threadIdx.x;
  if (e >= E_N) return;
  int s = edges[2 * e], d = edges[2 * e + 1];
  int p = atomicAdd(&cursor[s], 1);
  adj[csr_off[s] + p] = d;
  if (p < 8) adjell[s * 8 + p] = d;
  int q = atomicAdd(&cursor[d], 1);
  adj[csr_off[d] + q] = s;
  if (q < 8) adjell[d * 8 + q] = s;
}

// ----------------- gather: quad-per-vertex, dwordx4 row loads, packed-f16 math ----------
// Wave = 4 quads; quad q owns one vertex, lane l16 owns one 16B channel chunk (8 halves).
// MODE 0: neighbors from y (raw). MODE 1: neighbors from tin with relu(scale*t+shift),
//   where scale/shift are recomputed PER BLOCK from statsP (8 shards, written by the
//   previous gemm kernel; stream order = visibility, no fences). Blocks 0..7 zero statsN.
// ELL8 fast path; tail (deg > 8) walks CSR. Grid: 6250 x 4 waves x 4 quads = 100000.
template <int MODE>
__global__ __launch_bounds__(256) void k_gather(const f16* __restrict__ tin, const f16* __restrict__ y,
                                                f16* __restrict__ xa, const int* __restrict__ deg,
                                                const int* __restrict__ csr_off,
                                                const int* __restrict__ adjell, const int* __restrict__ adj,
                                                const float* __restrict__ gamma, const float* __restrict__ beta,
                                                const float* __restrict__ statsP, float* __restrict__ statsN) {
  __shared__ float sred[256];
  __shared__ float scl[128], sfl[128];
  int tid = threadIdx.x;
  if (blockIdx.x < NSH) statsN[blockIdx.x * 256 + tid] = 0.f;
  int w = tid >> 6, lane = tid & 63;
  int q = lane >> 4, l16 = lane & 15;
  int v = (blockIdx.x * 4 + w) * 4 + q;  // this lane's vertex (exactly covers [0, V_N))
  int co = l16 * 8;                      // channel base, 8 halves = 16B
  const f16* base = MODE ? tin : y;
  int dg = deg[v];
  int s0 = csr_off[v];
  int4 ia = *(const int4*)&adjell[v * 8];
  int4 ib = *(const int4*)&adjell[v * 8 + 4];
  f16x8 scv = {}, sfv = {};
  if (MODE) {
    // per-block redundant BN finalize (identical f32 math in every block)
    float a = 0.f;
#pragma unroll
    for (int h = 0; h < NSH; ++h) a += statsP[h * 256 + tid];
    sred[tid] = a;
    __syncthreads();
    if (tid < 128) {
      float s = sred[tid], sq = sred[128 + tid];
      float mu = s * (1.0f / V_N);
      float var = sq * (1.0f / V_N) - mu * mu;
      float scvf = gamma[tid] * rsqrtf(var + EPSV);
      scl[tid] = scvf;
      sfl[tid] = beta[tid] - mu * scvf;
    }
    __syncthreads();
#pragma unroll
    for (int k = 0; k < 8; ++k) {
      scv[k] = (f16)scl[co + k];
      sfv[k] = (f16)sfl[co + k];
    }
  }
  int idx[8] = {ia.x, ia.y, ia.z, ia.w, ib.x, ib.y, ib.z, ib.w};
#pragma unroll
  for (int j = 0; j < 8; ++j) idx[j] = ((unsigned)idx[j] < (unsigned)V_N) ? idx[j] : 0;
  f16x8 h[8];
#pragma unroll
  for (int j = 0; j < 8; ++j) h[j] = *(const f16x8*)&base[(size_t)idx[j] * 128 + co];
  f16x8 zero = {};
#pragma unroll
  for (int j = 0; j < 8; ++j) {
    f16x8 u = h[j];
    if (MODE) u = __builtin_elementwise_max(scv * u + sfv, zero);
    h[j] = (j < dg) ? u : zero;
  }
  f16x8 t01 = h[0] + h[1], t23 = h[2] + h[3], t45 = h[4] + h[5], t67 = h[6] + h[7];
  f16x8 sum = (t01 + t23) + (t45 + t67);
  float a[8];
#pragma unroll
  for (int k = 0; k < 8; ++k) a[k] = (float)sum[k];
  // tail for deg > 8 (divergent at quad granularity; P ~ 11% of vertices)
  for (int p = 8; p < dg; p += 8) {
    int id2[8];
#pragma unroll
    for (int j = 0; j < 8; ++j) {
      int pp = p + j;
      id2[j] = adj[s0 + (pp < dg ? pp : dg - 1)];
    }
    f16x8 g[8];
#pragma unroll
    for (int j = 0; j < 8; ++j) g[j] = *(const f16x8*)&base[(size_t)id2[j] * 128 + co];
#pragma unroll
    for (int j = 0; j < 8; ++j) {
      f16x8 u = g[j];
      if (MODE) u = __builtin_elementwise_max(scv * u + sfv, zero);
      g[j] = (p + j < dg) ? u : zero;
    }
    f16x8 s2 = ((g[0] + g[1]) + (g[2] + g[3])) + ((g[4] + g[5]) + (g[6] + g[7]));
#pragma unroll
    for (int k = 0; k < 8; ++k) a[k] += (float)s2[k];
  }
  f16x8 o;
#pragma unroll
  for (int k = 0; k < 8; ++k) o[k] = (f16)a[k];
  *(f16x8*)&xa[(size_t)v * 128 + co] = o;
}

// ----------------- fused GEMM: t = dinv * ([act|xa] @ Wcat^T + b0 + deg*b1); + BN stats ---
// 128 rows x 128 cols per block (782 blocks), K=256 in 4 chunks of 64 halves.
// Wave w owns rows {rg*64 + w*16 + l16 : rg=0,1}; B fragments shared across both row-groups.
// MODE 0: A y-half = ysrc (raw f16) via global_load_lds.
// MODE 1: A y-half reg-staged from ysrc(=t, in-place safe) with relu(scale*t+shift);
//   scale/shift recomputed per block from statsP (previous layer's stats, prev kernel).
// Stats for THIS layer go to statsN (8-way sharded, zeroed by the preceding gather).
template <int MODE>
__global__ __launch_bounds__(256) void k_gemm(const f16* ysrc, const f16* __restrict__ xa,
                                              const f16* __restrict__ Wc,
                                              const float* __restrict__ b0, const float* __restrict__ b1,
                                              const float* __restrict__ dinv, const float* __restrict__ degf,
                                              const float* __restrict__ gammaP, const float* __restrict__ betaP,
                                              const float* __restrict__ statsP, float* __restrict__ statsN,
                                              f16* tbuf) {
  __shared__ __align__(16) f16 As[128 * 64];   // 1024 x 16B chunks, chunk (r,c) at slot r*8 + (c^(r&7))
  __shared__ __align__(16) f16 Bs[128 * 64];   // 1024 x 16B chunks
  __shared__ float sstat[256];
  __shared__ __align__(16) f16 scf[128], shf[128];
  int tid = threadIdx.x;
  int w = tid >> 6, lane = tid & 63;
  int quad = lane >> 4, l16 = lane & 15;
  int row0 = blockIdx.x * 128;
  f32x4 acc[2][8] = {};
  if (MODE) {
    // per-block redundant BN finalize of the PREVIOUS layer (uses sstat as scratch)
    float a = 0.f;
#pragma unroll
    for (int h = 0; h < NSH; ++h) a += statsP[h * 256 + tid];
    sstat[tid] = a;
    __syncthreads();
    if (tid < 128) {
      float s = sstat[tid], sq = sstat[128 + tid];
      float mu = s * (1.0f / V_N);
      float var = sq * (1.0f / V_N) - mu * mu;
      float scv = gammaP[tid] * rsqrtf(var + EPSV);
      scf[tid] = (f16)scv;
      shf[tid] = (f16)(betaP[tid] - mu * scv);
    }
    __syncthreads();
  }
  sstat[tid] = 0.f;  // visible before epilogue use via the kc-loop barriers

  for (int kc = 0; kc < 4; ++kc) {
    if (MODE && kc < 2) {
      // reg-stage A from t with on-the-fly BN+relu (identical f16 math to gather's path)
      int koff = kc * 64;
      f16x8 zero = {};
#pragma unroll
      for (int i = 0; i < 4; ++i) {
        int s = (w * 4 + i) * 64 + lane;
        int r = s >> 3, c = (s & 7) ^ (r & 7);
        int ch = koff + c * 8;
        f16x8 u = *(const f16x8*)&ysrc[(size_t)(row0 + r) * 128 + ch];
        f16x8 sc8 = *(const f16x8*)&scf[ch];
        f16x8 sf8 = *(const f16x8*)&shf[ch];
        u = __builtin_elementwise_max(sc8 * u + sf8, zero);
        *(f16x8*)&As[s * 8] = u;
      }
    } else {
      const f16* Abase = (kc < 2) ? ysrc : xa;
      int koff = (kc & 1) * 64;
#pragma unroll
      for (int i = 0; i < 4; ++i) {
        int s = (w * 4 + i) * 64 + lane;
        int r = s >> 3, c = (s & 7) ^ (r & 7);
        GLD(Abase + (size_t)(row0 + r) * 128 + koff + c * 8, &As[(w * 4 + i) * 512]);
      }
    }
    // stage B: 1024 chunks, 4 per wave
#pragma unroll
    for (int i = 0; i < 4; ++i) {
      int s = (w * 4 + i) * 64 + lane;
      int r = s >> 3, c = (s & 7) ^ (r & 7);
      GLD(Wc + (size_t)r * 256 + kc * 64 + c * 8, &Bs[(w * 4 + i) * 512]);
    }
    __syncthreads();  // drains vmcnt (GLD) + lgkmcnt (ds_write) + barrier
#pragma unroll
    for (int ks = 0; ks < 2; ++ks) {
      int cc = ks * 4 + quad;
      f16x8 af0, af1;
      {
        int rr = w * 16 + l16;
        af0 = *(const f16x8*)&As[(rr * 8 + (cc ^ (rr & 7))) * 8];
        int rr1 = 64 + rr;
        af1 = *(const f16x8*)&As[(rr1 * 8 + (cc ^ (rr1 & 7))) * 8];
      }
#pragma unroll
      for (int ni = 0; ni < 8; ++ni) {
        int rb = ni * 16 + l16;
        f16x8 bf = *(const f16x8*)&Bs[(rb * 8 + (cc ^ (rb & 7))) * 8];
        acc[0][ni] = __builtin_amdgcn_mfma_f32_16x16x32_f16(af0, bf, acc[0][ni], 0, 0, 0);
        acc[1][ni] = __builtin_amdgcn_mfma_f32_16x16x32_f16(af1, bf, acc[1][ni], 0, 0, 0);
      }
    }
    __syncthreads();
  }

  float b0c[8], b1c[8];
#pragma unroll
  for (int ni = 0; ni < 8; ++ni) {
    b0c[ni] = b0[ni * 16 + l16];
    b1c[ni] = b1[ni * 16 + l16];
  }
  float csum[8] = {}, csq[8] = {};
  // C/D layout: col = l16, row = quad*4 + reg (within each row-group)
#pragma unroll
  for (int rg = 0; rg < 2; ++rg) {
#pragma unroll
    for (int reg = 0; reg < 4; ++reg) {
      int v = row0 + rg * 64 + w * 16 + quad * 4 + reg;
      if (v < V_N) {
        float dv = dinv[v], gf = degf[v];
#pragma unroll
        for (int ni = 0; ni < 8; ++ni) {
          float tv = dv * (acc[rg][ni][reg] + b0c[ni] + gf * b1c[ni]);
          tbuf[(size_t)v * 128 + ni * 16 + l16] = (f16)tv;
          csum[ni] += tv;
          csq[ni] += tv * tv;
        }
      }
    }
  }
#pragma unroll
  for (int ni = 0; ni < 8; ++ni) {
    csum[ni] += __shfl_xor(csum[ni], 16);
    csum[ni] += __shfl_xor(csum[ni], 32);
    csq[ni] += __shfl_xor(csq[ni], 16);
    csq[ni] += __shfl_xor(csq[ni], 32);
  }
  if (quad == 0) {
#pragma unroll
    for (int ni = 0; ni < 8; ++ni) {
      atomicAdd(&sstat[ni * 16 + l16], csum[ni]);
      atomicAdd(&sstat[128 + ni * 16 + l16], csq[ni]);
    }
  }
  __syncthreads();
  atomicAdd(&statsN[(blockIdx.x & (NSH - 1)) * 256 + tid], sstat[tid]);  // 8-way sharded
}

// ----------------- final: out = relu(scale*t + shift + features), scale/shift per block ---
__global__ __launch_bounds__(256) void k_final(const f16* __restrict__ t, const float* __restrict__ feat,
                                               const float* __restrict__ gamma, const float* __restrict__ beta,
                                               const float* __restrict__ stats, float* __restrict__ out) {
  __shared__ float sred[256];
  __shared__ float scl[128], sfl[128];
  int tid = threadIdx.x;
  float a = 0.f;
#pragma unroll
  for (int h = 0; h < NSH; ++h) a += stats[h * 256 + tid];
  sred[tid] = a;
  __syncthreads();
  if (tid < 128) {
    float s = sred[tid], sq = sred[128 + tid];
    float mu = s * (1.0f / V_N);
    float var = sq * (1.0f / V_N) - mu * mu;
    float scv = gamma[tid] * rsqrtf(var + EPSV);
    scl[tid] = scv;
    sfl[tid] = beta[tid] - mu * scv;
  }
  __syncthreads();
  int q = blockIdx.x * 256 + tid;  // float4 index; 12500*256 == V_N*32 exactly
  int c4 = (q & 31) * 4;
  f16x4 tv = *(const f16x4*)&t[(size_t)q * 4];
  float4 fv = ((const float4*)feat)[q];
  float4 o;
  o.x = fmaxf(scl[c4 + 0] * (float)tv[0] + sfl[c4 + 0] + fv.x, 0.f);
  o.y = fmaxf(scl[c4 + 1] * (float)tv[1] + sfl[c4 + 1] + fv.y, 0.f);
  o.z = fmaxf(scl[c4 + 2] * (float)tv[2] + sfl[c4 + 2] + fv.z, 0.f);
  o.w = fmaxf(scl[c4 + 3] * (float)tv[3] + sfl[c4 + 3] + fv.w, 0.f);
  ((float4*)out)[q] = o;
}

extern "C" void kernel_launch(void* const* d_in, const int* in_sizes, int n_in,
                              void* d_out, int out_size, void* d_ws, size_t ws_size,
                              hipStream_t stream) {
  const float* features = (const float*)d_in[0];
  const int* edges = (const int*)d_in[1];
  const float* W0 = (const float*)d_in[2];
  const float* b0 = (const float*)d_in[3];
  const float* W1 = (const float*)d_in[4];
  const float* b1 = (const float*)d_in[5];
  const float* gamma = (const float*)d_in[6];
  const float* beta = (const float*)d_in[7];
  float* out = (float*)d_out;

  char* ws = (char*)d_ws;
  size_t off = 0;
  auto alloc = [&](size_t bytes) -> void* {
    void* p = ws + off;
    off = (off + bytes + 255) & ~(size_t)255;
    return p;
  };
  int* deg = (int*)alloc((size_t)V_N * 4);
  int* cursor = (int*)alloc((size_t)V_N * 4);
  int* csr_off = (int*)alloc((size_t)(V_N + 1) * 4);
  int* adj = (int*)alloc((size_t)2 * E_N * 4);
  int* adjell = (int*)alloc((size_t)V_N * 8 * 4);
  float* dinv = (float*)alloc((size_t)V_N * 4);
  float* degf = (float*)alloc((size_t)V_N * 4);
  int* csum = (int*)alloc(512 * 4);
  int* coff = (int*)alloc(512 * 4);
  float* stats0 = (float*)alloc((size_t)NSH * 256 * 4);
  float* stats1 = (float*)alloc((size_t)NSH * 256 * 4);
  f16* y = (f16*)alloc((size_t)MPAD * 128 * 2);
  f16* xa = (f16*)alloc((size_t)MPAD * 128 * 2);
  f16* tbuf = (f16*)alloc((size_t)MPAD * 128 * 2);
  f16* Wcat = (f16*)alloc((size_t)3 * 128 * 256 * 2);

  // preamble: CSR + ELL8 + dinv/degf + weight prep + feature cast (6 dispatches)
  hipMemsetAsync(deg, 0, (size_t)V_N * 4, stream);
  k_countprep<<<2344 + 384 + 12500, 256, 0, stream>>>(edges, deg, W0, W1, Wcat, features, y);
  k_chunksum<<<NCHUNK, 256, 0, stream>>>(deg, csum);
  k_scanchunks<<<1, 512, 0, stream>>>(csum, coff);
  k_writeoff<<<NCHUNK, 256, 0, stream>>>(deg, coff, csr_off, dinv, degf, cursor);
  k_fill<<<(E_N + 255) / 256, 256, 0, stream>>>(edges, csr_off, cursor, adj, adjell);

  // layer 0: gather from y; gemm A y-half via GLD; stats -> stats0 (zeroed by gather<0>)
  k_gather<0><<<6250, 256, 0, stream>>>(tbuf, y, xa, deg, csr_off, adjell, adj,
                                        gamma, beta, stats0, stats0);
  k_gemm<0><<<NBLK_G, 256, 0, stream>>>(y, xa, Wcat, b0, b1, dinv, degf,
                                        gamma, beta, stats0, stats0, tbuf);
  // layer 1: BN(layer0) from stats0; stats -> stats1
  k_gather<1><<<6250, 256, 0, stream>>>(tbuf, y, xa, deg, csr_off, adjell, adj,
                                        gamma, beta, stats0, stats1);
  k_gemm<1><<<NBLK_G, 256, 0, stream>>>(tbuf, xa, Wcat + (size_t)1 * 128 * 256, b0 + D_N,
                                        b1 + D_N, dinv, degf, gamma, beta, stats0, stats1, tbuf);
  // layer 2: BN(layer1) from stats1; stats -> stats0
  k_gather<1><<<6250, 256, 0, stream>>>(tbuf, y, xa, deg, csr_off, adjell, adj,
                                        gamma + D_N, beta + D_N, stats1, stats0);
  k_gemm<1><<<NBLK_G, 256, 0, stream>>>(tbuf, xa, Wcat + (size_t)2 * 128 * 256, b0 + 2 * D_N,
                                        b1 + 2 * D_N, dinv, degf, gamma + D_N, beta + D_N,
                                        stats1, stats0, tbuf);
  // final: BN(layer2) from stats0 + residual + relu
  k_final<<<12500, 256, 0, stream>>>(tbuf, features, gamma + 2 * D_N, beta + 2 * D_N, stats0, out);
}

// Round 9
// 328.801 us; speedup vs baseline: 1.9561x; 1.0181x over previous
//
#include <hip/hip_runtime.h>
#include <math.h>
#include <stdint.h>

#define V_N 100000
#define E_N 300000
#define D_N 128
#define EPSV 1e-5f
#define NCHUNK 391   // ceil(V_N/256)
#define MPAD 100096  // 1564 * 64
#define NBLK_G 782   // MPAD/128 gemm blocks (128-row tiles)
#define NSH 8        // stats shards

typedef _Float16 f16;
typedef f16 f16x8 __attribute__((ext_vector_type(8)));
typedef f16 f16x4 __attribute__((ext_vector_type(4)));
typedef f16 f16x2 __attribute__((ext_vector_type(2)));
typedef float f32x4 __attribute__((ext_vector_type(4)));

// async global->LDS, 16B per lane; lds base must be wave-uniform
#define GLD(g, l) __builtin_amdgcn_global_load_lds( \
    (__attribute__((address_space(1))) void*)(g),   \
    (__attribute__((address_space(3))) void*)(l), 16, 0, 0)

// ----------------- merged: edge-degree count + weight prep + feature cast -----------------
// blocks [0,2344): count; [2344,2728): Wcat[l][n][k] half, k=[W0 row|W1 row]; rest: f16 cast.
__global__ __launch_bounds__(256) void k_countprep(const int* __restrict__ edges, int* __restrict__ deg,
                                                   const float* __restrict__ W0, const float* __restrict__ W1,
                                                   f16* __restrict__ Wc, const float* __restrict__ x,
                                                   f16* __restrict__ y) {
  int b = blockIdx.x;
  if (b < 2344) {
    int i = b * 256 + threadIdx.x;
    if (i < 2 * E_N) atomicAdd(&deg[edges[i]], 1);
  } else if (b < 2344 + 384) {  // 384*256 == 3*128*256 exactly
    int idx = (b - 2344) * 256 + threadIdx.x;
    int l = idx >> 15;
    int rem = idx & 32767;
    int n = rem >> 8, k = rem & 255;
    float v = (k < 128) ? W0[l * 16384 + n * 128 + k] : W1[l * 16384 + n * 128 + (k - 128)];
    Wc[idx] = (f16)v;
  } else {
    int q = (b - 2344 - 384) * 256 + threadIdx.x;  // 12500*256 == V_N*32 exactly
    float4 xv = ((const float4*)x)[q];
    f16x4 h;
    h[0] = (f16)xv.x; h[1] = (f16)xv.y; h[2] = (f16)xv.z; h[3] = (f16)xv.w;
    *(f16x4*)&y[(size_t)q * 4] = h;
  }
}

__global__ __launch_bounds__(256) void k_chunksum(const int* __restrict__ deg, int* __restrict__ csum) {
  __shared__ int red[256];
  int c = blockIdx.x, t = threadIdx.x;
  int i = c * 256 + t;
  red[t] = (i < V_N) ? deg[i] : 0;
  __syncthreads();
  for (int s = 128; s > 0; s >>= 1) {
    if (t < s) red[t] += red[t + s];
    __syncthreads();
  }
  if (t == 0) csum[c] = red[0];
}

// per-block redundant chunk-offset (sum csum[j<c], L2-hot) replaces the k_scanchunks
// dispatch; then intra-chunk scan. Also zeroes the fill cursor (deg stays = true degree).
__global__ __launch_bounds__(256) void k_writeoff(const int* __restrict__ deg, const int* __restrict__ csum,
                                                  int* __restrict__ csr_off, float* __restrict__ dinv,
                                                  float* __restrict__ degf, int* __restrict__ cursor) {
  __shared__ int sh[256];
  __shared__ int sbase;
  int c = blockIdx.x, t = threadIdx.x;
  // exclusive chunk offset: sum of csum[0..c-1]
  int x = (t < c) ? csum[t] : 0;
  if (256 + t < c) x += csum[256 + t];  // c <= 390 < 512
  sh[t] = x;
  __syncthreads();
  for (int s = 128; s > 0; s >>= 1) {
    if (t < s) sh[t] += sh[t + s];
    __syncthreads();
  }
  if (t == 0) sbase = sh[0];
  __syncthreads();
  int base = sbase;
  __syncthreads();  // done reading sh[0]; safe to reuse sh
  int i = c * 256 + t;
  int v = (i < V_N) ? deg[i] : 0;
  sh[t] = v;
  __syncthreads();
  for (int s = 1; s < 256; s <<= 1) {
    int xx = (t >= s) ? sh[t - s] : 0;
    __syncthreads();
    sh[t] += xx;
    __syncthreads();
  }
  int excl = sh[t] - v;
  if (i <= V_N) csr_off[i] = base + excl;
  if (i < V_N) {
    dinv[i] = 1.0f / (1.0f + (float)v);
    degf[i] = (float)v;
    cursor[i] = 0;
  }
}

// fills CSR adj AND the ELL8 fast-path array (first 8 neighbors at adjell[v*8+j]).
// Slots j >= deg stay uninitialized (workspace garbage) -> consumer clamps before use.
__global__ __launch_bounds__(256) void k_fill(const int* __restrict__ edges, const int* __restrict__ csr_off,
                                              int* __restrict__ cursor, int* __restrict__ adj,
                                              int* __restrict__ adjell) {
  int e = blockIdx.x * blockDim.x + threadIdx.x;
  if (e >= E_N) return;
  int s = edges[2 * e], d = edges[2 * e + 1];
  int p = atomicAdd(&cursor[s], 1);
  adj[csr_off[s] + p] = d;
  if (p < 8) adjell[s * 8 + p] = d;
  int q = atomicAdd(&cursor[d], 1);
  adj[csr_off[d] + q] = s;
  if (q < 8) adjell[d * 8 + q] = s;
}

// ----------------- gather: quad-per-vertex, dwordx4 row loads, packed-f16 math ----------
// Wave = 4 quads; quad q owns one vertex, lane l16 owns one 16B channel chunk (8 halves).
// MODE 0: neighbors from y (raw). MODE 1: neighbors from tin with relu(scale*t+shift),
//   scale/shift recomputed per block from statsP (8 shards from the previous gemm).
// f16 accumulation throughout (deg<=8 path is bit-identical to the old f32 round-trip;
// tail adds in f16). __launch_bounds__(256,8) pins <=64 VGPR -> 32 waves/CU.
// Blocks 0..7 zero statsN. Grid: 6250 x 4 waves x 4 quads = 100000.
template <int MODE>
__global__ __launch_bounds__(256, 8) void k_gather(const f16* __restrict__ tin, const f16* __restrict__ y,
                                                   f16* __restrict__ xa, const int* __restrict__ deg,
                                                   const int* __restrict__ csr_off,
                                                   const int* __restrict__ adjell, const int* __restrict__ adj,
                                                   const float* __restrict__ gamma, const float* __restrict__ beta,
                                                   const float* __restrict__ statsP, float* __restrict__ statsN) {
  __shared__ float sred[256];
  __shared__ float scl[128], sfl[128];
  int tid = threadIdx.x;
  if (blockIdx.x < NSH) statsN[blockIdx.x * 256 + tid] = 0.f;
  int w = tid >> 6, lane = tid & 63;
  int q = lane >> 4, l16 = lane & 15;
  int v = (blockIdx.x * 4 + w) * 4 + q;  // this lane's vertex (exactly covers [0, V_N))
  int co = l16 * 8;                      // channel base, 8 halves = 16B
  const f16* base = MODE ? tin : y;
  int dg = deg[v];
  int s0 = csr_off[v];
  int4 ia = *(const int4*)&adjell[v * 8];
  int4 ib = *(const int4*)&adjell[v * 8 + 4];
  f16x8 scv = {}, sfv = {};
  if (MODE) {
    // per-block redundant BN finalize (identical f32 math in every block)
    float a = 0.f;
#pragma unroll
    for (int h = 0; h < NSH; ++h) a += statsP[h * 256 + tid];
    sred[tid] = a;
    __syncthreads();
    if (tid < 128) {
      float s = sred[tid], sq = sred[128 + tid];
      float mu = s * (1.0f / V_N);
      float var = sq * (1.0f / V_N) - mu * mu;
      float scvf = gamma[tid] * rsqrtf(var + EPSV);
      scl[tid] = scvf;
      sfl[tid] = beta[tid] - mu * scvf;
    }
    __syncthreads();
#pragma unroll
    for (int k = 0; k < 8; ++k) {
      scv[k] = (f16)scl[co + k];
      sfv[k] = (f16)sfl[co + k];
    }
  }
  int idx[8] = {ia.x, ia.y, ia.z, ia.w, ib.x, ib.y, ib.z, ib.w};
#pragma unroll
  for (int j = 0; j < 8; ++j) idx[j] = ((unsigned)idx[j] < (unsigned)V_N) ? idx[j] : 0;
  f16x8 h[8];
#pragma unroll
  for (int j = 0; j < 8; ++j) h[j] = *(const f16x8*)&base[(size_t)idx[j] * 128 + co];
  f16x8 zero = {};
#pragma unroll
  for (int j = 0; j < 8; ++j) {
    f16x8 u = h[j];
    if (MODE) u = __builtin_elementwise_max(scv * u + sfv, zero);
    h[j] = (j < dg) ? u : zero;
  }
  f16x8 t01 = h[0] + h[1], t23 = h[2] + h[3], t45 = h[4] + h[5], t67 = h[6] + h[7];
  f16x8 accv = (t01 + t23) + (t45 + t67);
  // tail for deg > 8 (divergent at quad granularity; P ~ 11% of vertices)
  for (int p = 8; p < dg; p += 8) {
    int id2[8];
#pragma unroll
    for (int j = 0; j < 8; ++j) {
      int pp = p + j;
      id2[j] = adj[s0 + (pp < dg ? pp : dg - 1)];
    }
    f16x8 g[8];
#pragma unroll
    for (int j = 0; j < 8; ++j) g[j] = *(const f16x8*)&base[(size_t)id2[j] * 128 + co];
#pragma unroll
    for (int j = 0; j < 8; ++j) {
      f16x8 u = g[j];
      if (MODE) u = __builtin_elementwise_max(scv * u + sfv, zero);
      g[j] = (p + j < dg) ? u : zero;
    }
    accv = accv + (((g[0] + g[1]) + (g[2] + g[3])) + ((g[4] + g[5]) + (g[6] + g[7])));
  }
  *(f16x8*)&xa[(size_t)v * 128 + co] = accv;
}

// ----------------- fused GEMM: t = dinv * ([act|xa] @ Wcat^T + b0 + deg*b1); + BN stats ---
// 128 rows x 128 cols per block (782 blocks), K=256 in 4 chunks of 64 halves.
// Wave w owns rows {rg*64 + w*16 + l16 : rg=0,1}; B fragments shared across both row-groups.
// MODE 0: A y-half = ysrc (raw f16) via global_load_lds.
// MODE 1: A y-half reg-staged from ysrc(=t, in-place safe) with relu(scale*t+shift);
//   scale/shift recomputed per block from statsP (previous layer's stats, prev kernel).
// Stats for THIS layer go to statsN (8-way sharded, zeroed by the preceding gather).
template <int MODE>
__global__ __launch_bounds__(256) void k_gemm(const f16* ysrc, const f16* __restrict__ xa,
                                              const f16* __restrict__ Wc,
                                              const float* __restrict__ b0, const float* __restrict__ b1,
                                              const float* __restrict__ dinv, const float* __restrict__ degf,
                                              const float* __restrict__ gammaP, const float* __restrict__ betaP,
                                              const float* __restrict__ statsP, float* __restrict__ statsN,
                                              f16* tbuf) {
  __shared__ __align__(16) f16 As[128 * 64];   // 1024 x 16B chunks, chunk (r,c) at slot r*8 + (c^(r&7))
  __shared__ __align__(16) f16 Bs[128 * 64];   // 1024 x 16B chunks
  __shared__ float sstat[256];
  __shared__ __align__(16) f16 scf[128], shf[128];
  int tid = threadIdx.x;
  int w = tid >> 6, lane = tid & 63;
  int quad = lane >> 4, l16 = lane & 15;
  int row0 = blockIdx.x * 128;
  f32x4 acc[2][8] = {};
  if (MODE) {
    // per-block redundant BN finalize of the PREVIOUS layer (uses sstat as scratch)
    float a = 0.f;
#pragma unroll
    for (int h = 0; h < NSH; ++h) a += statsP[h * 256 + tid];
    sstat[tid] = a;
    __syncthreads();
    if (tid < 128) {
      float s = sstat[tid], sq = sstat[128 + tid];
      float mu = s * (1.0f / V_N);
      float var = sq * (1.0f / V_N) - mu * mu;
      float scv = gammaP[tid] * rsqrtf(var + EPSV);
      scf[tid] = (f16)scv;
      shf[tid] = (f16)(betaP[tid] - mu * scv);
    }
    __syncthreads();
  }
  sstat[tid] = 0.f;  // visible before epilogue use via the kc-loop barriers

  for (int kc = 0; kc < 4; ++kc) {
    if (MODE && kc < 2) {
      // reg-stage A from t with on-the-fly BN+relu (identical f16 math to gather's path)
      int koff = kc * 64;
      f16x8 zero = {};
#pragma unroll
      for (int i = 0; i < 4; ++i) {
        int s = (w * 4 + i) * 64 + lane;
        int r = s >> 3, c = (s & 7) ^ (r & 7);
        int ch = koff + c * 8;
        f16x8 u = *(const f16x8*)&ysrc[(size_t)(row0 + r) * 128 + ch];
        f16x8 sc8 = *(const f16x8*)&scf[ch];
        f16x8 sf8 = *(const f16x8*)&shf[ch];
        u = __builtin_elementwise_max(sc8 * u + sf8, zero);
        *(f16x8*)&As[s * 8] = u;
      }
    } else {
      const f16* Abase = (kc < 2) ? ysrc : xa;
      int koff = (kc & 1) * 64;
#pragma unroll
      for (int i = 0; i < 4; ++i) {
        int s = (w * 4 + i) * 64 + lane;
        int r = s >> 3, c = (s & 7) ^ (r & 7);
        GLD(Abase + (size_t)(row0 + r) * 128 + koff + c * 8, &As[(w * 4 + i) * 512]);
      }
    }
    // stage B: 1024 chunks, 4 per wave
#pragma unroll
    for (int i = 0; i < 4; ++i) {
      int s = (w * 4 + i) * 64 + lane;
      int r = s >> 3, c = (s & 7) ^ (r & 7);
      GLD(Wc + (size_t)r * 256 + kc * 64 + c * 8, &Bs[(w * 4 + i) * 512]);
    }
    __syncthreads();  // drains vmcnt (GLD) + lgkmcnt (ds_write) + barrier
#pragma unroll
    for (int ks = 0; ks < 2; ++ks) {
      int cc = ks * 4 + quad;
      f16x8 af0, af1;
      {
        int rr = w * 16 + l16;
        af0 = *(const f16x8*)&As[(rr * 8 + (cc ^ (rr & 7))) * 8];
        int rr1 = 64 + rr;
        af1 = *(const f16x8*)&As[(rr1 * 8 + (cc ^ (rr1 & 7))) * 8];
      }
#pragma unroll
      for (int ni = 0; ni < 8; ++ni) {
        int rb = ni * 16 + l16;
        f16x8 bf = *(const f16x8*)&Bs[(rb * 8 + (cc ^ (rb & 7))) * 8];
        acc[0][ni] = __builtin_amdgcn_mfma_f32_16x16x32_f16(af0, bf, acc[0][ni], 0, 0, 0);
        acc[1][ni] = __builtin_amdgcn_mfma_f32_16x16x32_f16(af1, bf, acc[1][ni], 0, 0, 0);
      }
    }
    __syncthreads();
  }

  float b0c[8], b1c[8];
#pragma unroll
  for (int ni = 0; ni < 8; ++ni) {
    b0c[ni] = b0[ni * 16 + l16];
    b1c[ni] = b1[ni * 16 + l16];
  }
  float csum[8] = {}, csq[8] = {};
  // C/D layout: col = l16, row = quad*4 + reg (within each row-group)
#pragma unroll
  for (int rg = 0; rg < 2; ++rg) {
#pragma unroll
    for (int reg = 0; reg < 4; ++reg) {
      int v = row0 + rg * 64 + w * 16 + quad * 4 + reg;
      if (v < V_N) {
        float dv = dinv[v], gf = degf[v];
#pragma unroll
        for (int ni = 0; ni < 8; ++ni) {
          float tv = dv * (acc[rg][ni][reg] + b0c[ni] + gf * b1c[ni]);
          tbuf[(size_t)v * 128 + ni * 16 + l16] = (f16)tv;
          csum[ni] += tv;
          csq[ni] += tv * tv;
        }
      }
    }
  }
#pragma unroll
  for (int ni = 0; ni < 8; ++ni) {
    csum[ni] += __shfl_xor(csum[ni], 16);
    csum[ni] += __shfl_xor(csum[ni], 32);
    csq[ni] += __shfl_xor(csq[ni], 16);
    csq[ni] += __shfl_xor(csq[ni], 32);
  }
  if (quad == 0) {
#pragma unroll
    for (int ni = 0; ni < 8; ++ni) {
      atomicAdd(&sstat[ni * 16 + l16], csum[ni]);
      atomicAdd(&sstat[128 + ni * 16 + l16], csq[ni]);
    }
  }
  __syncthreads();
  atomicAdd(&statsN[(blockIdx.x & (NSH - 1)) * 256 + tid], sstat[tid]);  // 8-way sharded
}

// ----------------- final: out = relu(scale*t + shift + res), res from f16 y -----------------
__global__ __launch_bounds__(256) void k_final(const f16* __restrict__ t, const f16* __restrict__ yres,
                                               const float* __restrict__ gamma, const float* __restrict__ beta,
                                               const float* __restrict__ stats, float* __restrict__ out) {
  __shared__ float sred[256];
  __shared__ float scl[128], sfl[128];
  int tid = threadIdx.x;
  float a = 0.f;
#pragma unroll
  for (int h = 0; h < NSH; ++h) a += stats[h * 256 + tid];
  sred[tid] = a;
  __syncthreads();
  if (tid < 128) {
    float s = sred[tid], sq = sred[128 + tid];
    float mu = s * (1.0f / V_N);
    float var = sq * (1.0f / V_N) - mu * mu;
    float scv = gamma[tid] * rsqrtf(var + EPSV);
    scl[tid] = scv;
    sfl[tid] = beta[tid] - mu * scv;
  }
  __syncthreads();
  int q = blockIdx.x * 256 + tid;  // float4 index; 12500*256 == V_N*32 exactly
  int c4 = (q & 31) * 4;
  f16x4 tv = *(const f16x4*)&t[(size_t)q * 4];
  f16x4 rv = *(const f16x4*)&yres[(size_t)q * 4];
  float4 o;
  o.x = fmaxf(scl[c4 + 0] * (float)tv[0] + sfl[c4 + 0] + (float)rv[0], 0.f);
  o.y = fmaxf(scl[c4 + 1] * (float)tv[1] + sfl[c4 + 1] + (float)rv[1], 0.f);
  o.z = fmaxf(scl[c4 + 2] * (float)tv[2] + sfl[c4 + 2] + (float)rv[2], 0.f);
  o.w = fmaxf(scl[c4 + 3] * (float)tv[3] + sfl[c4 + 3] + (float)rv[3], 0.f);
  ((float4*)out)[q] = o;
}

extern "C" void kernel_launch(void* const* d_in, const int* in_sizes, int n_in,
                              void* d_out, int out_size, void* d_ws, size_t ws_size,
                              hipStream_t stream) {
  const float* features = (const float*)d_in[0];
  const int* edges = (const int*)d_in[1];
  const float* W0 = (const float*)d_in[2];
  const float* b0 = (const float*)d_in[3];
  const float* W1 = (const float*)d_in[4];
  const float* b1 = (const float*)d_in[5];
  const float* gamma = (const float*)d_in[6];
  const float* beta = (const float*)d_in[7];
  float* out = (float*)d_out;

  char* ws = (char*)d_ws;
  size_t off = 0;
  auto alloc = [&](size_t bytes) -> void* {
    void* p = ws + off;
    off = (off + bytes + 255) & ~(size_t)255;
    return p;
  };
  int* deg = (int*)alloc((size_t)V_N * 4);
  int* cursor = (int*)alloc((size_t)V_N * 4);
  int* csr_off = (int*)alloc((size_t)(V_N + 1) * 4);
  int* adj = (int*)alloc((size_t)2 * E_N * 4);
  int* adjell = (int*)alloc((size_t)V_N * 8 * 4);
  float* dinv = (float*)alloc((size_t)V_N * 4);
  float* degf = (float*)alloc((size_t)V_N * 4);
  int* csum = (int*)alloc(512 * 4);
  float* stats0 = (float*)alloc((size_t)NSH * 256 * 4);
  float* stats1 = (float*)alloc((size_t)NSH * 256 * 4);
  f16* y = (f16*)alloc((size_t)MPAD * 128 * 2);
  f16* xa = (f16*)alloc((size_t)MPAD * 128 * 2);
  f16* tbuf = (f16*)alloc((size_t)MPAD * 128 * 2);
  f16* Wcat = (f16*)alloc((size_t)3 * 128 * 256 * 2);

  // preamble: CSR + ELL8 + dinv/degf + weight prep + feature cast (5 dispatches)
  hipMemsetAsync(deg, 0, (size_t)V_N * 4, stream);
  k_countprep<<<2344 + 384 + 12500, 256, 0, stream>>>(edges, deg, W0, W1, Wcat, features, y);
  k_chunksum<<<NCHUNK, 256, 0, stream>>>(deg, csum);
  k_writeoff<<<NCHUNK, 256, 0, stream>>>(deg, csum, csr_off, dinv, degf, cursor);
  k_fill<<<(E_N + 255) / 256, 256, 0, stream>>>(edges, csr_off, cursor, adj, adjell);

  // layer 0: gather from y; gemm A y-half via GLD; stats -> stats0 (zeroed by gather<0>)
  k_gather<0><<<6250, 256, 0, stream>>>(tbuf, y, xa, deg, csr_off, adjell, adj,
                                        gamma, beta, stats0, stats0);
  k_gemm<0><<<NBLK_G, 256, 0, stream>>>(y, xa, Wcat, b0, b1, dinv, degf,
                                        gamma, beta, stats0, stats0, tbuf);
  // layer 1: BN(layer0) from stats0; stats -> stats1
  k_gather<1><<<6250, 256, 0, stream>>>(tbuf, y, xa, deg, csr_off, adjell, adj,
                                        gamma, beta, stats0, stats1);
  k_gemm<1><<<NBLK_G, 256, 0, stream>>>(tbuf, xa, Wcat + (size_t)1 * 128 * 256, b0 + D_N,
                                        b1 + D_N, dinv, degf, gamma, beta, stats0, stats1, tbuf);
  // layer 2: BN(layer1) from stats1; stats -> stats0
  k_gather<1><<<6250, 256, 0, stream>>>(tbuf, y, xa, deg, csr_off, adjell, adj,
                                        gamma + D_N, beta + D_N, stats1, stats0);
  k_gemm<1><<<NBLK_G, 256, 0, stream>>>(tbuf, xa, Wcat + (size_t)2 * 128 * 256, b0 + 2 * D_N,
                                        b1 + 2 * D_N, dinv, degf, gamma + D_N, beta + D_N,
                                        stats1, stats0, tbuf);
  // final: BN(layer2) from stats0 + residual (f16 y) + relu
  k_final<<<12500, 256, 0, stream>>>(tbuf, y, gamma + 2 * D_N, beta + 2 * D_N, stats0, out);
}